// Round 3
// baseline (3008.694 us; speedup 1.0000x reference)
//
#include <hip/hip_runtime.h>

// LatentGuidedEdgeDecoder — round 6: deepen weight-load pipeline (MLP fix).
// R5 counters: dur 2155us, VALUBusy 45.5%, Occupancy 48%, VGPR=48(!), HBM 1.6%,
// bank-conflicts negligible. Diagnosis: VALU idle 55% because only ~3 weight
// float4 loads in flight per wave (VGPR=48 can't hold a k-block); waves stall on
// vmcnt after every few loads. Budget is 128 VGPR at 4 waves/SIMD.
// R6: gemm16 rewritten with explicit register double-buffering:
//   * two 2-k-row weight buffers (2 x 8 float4 = 64 VGPR) ping-pong,
//     prefetch distance = 1 block (~64 VALU cycles; x4 waves = ~256 cyc cover).
//   * x read as one float4 per 4 k-rows, double-buffered (4x fewer LDS ops
//     than scalar reads; LDS pipe ~35% of VALU time, off critical path).
//   * steady-state loop body has NO branches: prefetch ranges proven by the
//     loop bound (main loop ends at K-4; tail peeled, no loads).
// Everything else (64 rows/block, 16 waves x 16 cols, lane==row, LN exchange,
// dtype dispatch, bf16->f32 weight conv) identical to R5 (verified).

typedef __bf16 bf16;
#define HD 256
#define RPB 64
#define AST 260
#define TPB 1024
#define CONV_OFF 32768
#define CONV_FLOATS 957064
#define WS_NEED (CONV_OFF + CONV_FLOATS * 4)

__device__ __forceinline__ float bf2f(unsigned short u) {
  union { unsigned int i; float f; } c; c.i = ((unsigned)u) << 16; return c.f;
}
__device__ __forceinline__ float4 ld4c(const float* p) { return *(const float4*)p; }
__device__ __forceinline__ float4 ld4c(const bf16* p) {
  ushort4 u = *(const ushort4*)p;
  return make_float4(bf2f(u.x), bf2f(u.y), bf2f(u.z), bf2f(u.w));
}
template <class T>
__device__ __forceinline__ float ld(const T* __restrict__ p) { return (float)*p; }

// ---------------- dtype detector ----------------
__global__ void k_detect(const unsigned int* __restrict__ wds, int* __restrict__ flag, int nw) {
  __shared__ int sRed[4];
  int t = threadIdx.x;
  int cnt = 0;
  for (int i = t; i < nw; i += 256) {
    unsigned e = (wds[i] >> 7) & 0xFFu;
    cnt += (e >= 110u && e <= 140u) ? 1 : 0;
  }
#pragma unroll
  for (int m = 1; m < 64; m <<= 1) cnt += __shfl_xor(cnt, m);
  if ((t & 63) == 0) sRed[t >> 6] = cnt;
  __syncthreads();
  if (t == 0) flag[0] = (sRed[0] + sRed[1] + sRed[2] + sRed[3] > nw / 2) ? 1 : 0;
}

// ---------------- attention collapse precompute ----------------
template <class T, int WANT>
__global__ void k_cvo_a(const int* __restrict__ flag, const T* __restrict__ Wc,
                        const T* __restrict__ Wv, const T* __restrict__ bc,
                        const T* __restrict__ bv, float* __restrict__ tmp) {
  if (*flag != WANT) return;
  int i = blockIdx.x;
  int m = threadIdx.x;
  float s = 0.f;
  if (i < 8) {
    for (int u = 0; u < 256; ++u) s += ld(Wc + i * 256 + u) * ld(Wv + (size_t)u * 256 + m);
  } else {
    for (int u = 0; u < 256; ++u) s += ld(bc + u) * ld(Wv + (size_t)u * 256 + m);
    s += ld(bv + m);
  }
  tmp[i * 256 + m] = s;
}

template <class T, int WANT>
__global__ void k_cvo_b(const int* __restrict__ flag, const float* __restrict__ tmp,
                        const T* __restrict__ Wo, const T* __restrict__ bo,
                        float* __restrict__ Wcvo, float* __restrict__ bcvo) {
  if (*flag != WANT) return;
  int i = blockIdx.x;
  int m = threadIdx.x;
  float s = 0.f;
  const float* tr = tmp + i * 256;
  for (int u = 0; u < 256; ++u) s += tr[u] * ld(Wo + (size_t)u * 256 + m);
  if (i < 8) Wcvo[i * 256 + m] = s;
  else       bcvo[m] = s + ld(bo + m);
}

// ---------------- bf16 -> f32 weight conversion (bf16 world only) ----------------
__global__ void k_conv(const int* __restrict__ flag,
                       const bf16* s0, const bf16* s1, const bf16* s2, const bf16* s3,
                       const bf16* s4, const bf16* s5, const bf16* s6, const bf16* s7,
                       const bf16* s8, const bf16* s9, const bf16* s10, const bf16* s11,
                       const bf16* s12, const bf16* s13, const bf16* s14, const bf16* s15,
                       const bf16* s16, const bf16* s17, const bf16* s18,
                       float* __restrict__ dst) {
  if (*flag != 1) return;
  const bf16* srcs[19] = {s0,s1,s2,s3,s4,s5,s6,s7,s8,s9,s10,s11,s12,s13,s14,s15,s16,s17,s18};
  const int offs[20] = {0,131072,131328,131584,131840,132096,132352,134400,527616,528384,
                        724992,725760,922368,922624,922880,923136,955904,956032,957056,957064};
  int t = blockIdx.x * blockDim.x + threadIdx.x;
  int np = gridDim.x * blockDim.x;
#pragma unroll
  for (int seg = 0; seg < 19; ++seg) {
    const unsigned short* s = (const unsigned short*)srcs[seg];
    float* d = dst + offs[seg];
    int n = offs[seg + 1] - offs[seg];
    for (int i = t; i < n; i += np) d[i] = bf2f(s[i]);
  }
}

// ---------------- pipelined GEMM: acc[0..15] += sum_k x[k] * W[k][cb..cb+15] ----------------
// Register double-buffered: 2-k-row blocks (8 float4 each), x as float4 per 4 rows.
// K must be a multiple of 8 in the main path (256) or equal to 8.
template <int K, int LDW, class XT, class WT>
__device__ __forceinline__ void gemm16(float* __restrict__ acc, const XT* __restrict__ x,
                                       const WT* __restrict__ wb) {
  float4 wA[8], wB[8];
  float4 xCur, xNxt;
  auto LD = [&](float4* wv, int k) {
    const WT* wp = wb + (size_t)k * LDW;
#pragma unroll
    for (int j = 0; j < 4; ++j) wv[j] = ld4c(wp + j * 4);
#pragma unroll
    for (int j = 0; j < 4; ++j) wv[4 + j] = ld4c(wp + LDW + j * 4);
  };
  auto FMA2 = [&](const float4* wv, float xs0, float xs1) {
#pragma unroll
    for (int j = 0; j < 4; ++j) {
      const float4 wq = wv[j];
      acc[j*4+0] = fmaf(xs0, wq.x, acc[j*4+0]);
      acc[j*4+1] = fmaf(xs0, wq.y, acc[j*4+1]);
      acc[j*4+2] = fmaf(xs0, wq.z, acc[j*4+2]);
      acc[j*4+3] = fmaf(xs0, wq.w, acc[j*4+3]);
    }
#pragma unroll
    for (int j = 0; j < 4; ++j) {
      const float4 wq = wv[4 + j];
      acc[j*4+0] = fmaf(xs1, wq.x, acc[j*4+0]);
      acc[j*4+1] = fmaf(xs1, wq.y, acc[j*4+1]);
      acc[j*4+2] = fmaf(xs1, wq.z, acc[j*4+2]);
      acc[j*4+3] = fmaf(xs1, wq.w, acc[j*4+3]);
    }
  };
  // prologue: block A = rows 0-1, block B = rows 2-3, xCur = x[0..3]
  LD(wA, 0);
  LD(wB, 2);
  {
    float4 xt;
    xt.x = (float)x[0]; xt.y = (float)x[1]; xt.z = (float)x[2]; xt.w = (float)x[3];
    xCur = xt;
  }
  // main loop: all prefetches in-range by construction (no branches in body)
  int k2 = 0;
  for (; k2 < K - 4; k2 += 4) {
    {
      float4 xt;
      xt.x = (float)x[k2+4]; xt.y = (float)x[k2+5]; xt.z = (float)x[k2+6]; xt.w = (float)x[k2+7];
      xNxt = xt;
    }
    FMA2(wA, xCur.x, xCur.y);
    LD(wA, k2 + 4);
    FMA2(wB, xCur.z, xCur.w);
    LD(wB, k2 + 6);
    xCur = xNxt;
  }
  // tail: rows K-4..K-1, no prefetch
  FMA2(wA, xCur.x, xCur.y);
  FMA2(wB, xCur.z, xCur.w);
}

// f32-x fast path: x is f32 (LDS or conv weights) -> vector float4 read
template <int K, int LDW, class WT>
__device__ __forceinline__ void gemm16(float* __restrict__ acc, const float* __restrict__ x,
                                       const WT* __restrict__ wb) {
  float4 wA[8], wB[8];
  float4 xCur, xNxt;
  auto LD = [&](float4* wv, int k) {
    const WT* wp = wb + (size_t)k * LDW;
#pragma unroll
    for (int j = 0; j < 4; ++j) wv[j] = ld4c(wp + j * 4);
#pragma unroll
    for (int j = 0; j < 4; ++j) wv[4 + j] = ld4c(wp + LDW + j * 4);
  };
  auto FMA2 = [&](const float4* wv, float xs0, float xs1) {
#pragma unroll
    for (int j = 0; j < 4; ++j) {
      const float4 wq = wv[j];
      acc[j*4+0] = fmaf(xs0, wq.x, acc[j*4+0]);
      acc[j*4+1] = fmaf(xs0, wq.y, acc[j*4+1]);
      acc[j*4+2] = fmaf(xs0, wq.z, acc[j*4+2]);
      acc[j*4+3] = fmaf(xs0, wq.w, acc[j*4+3]);
    }
#pragma unroll
    for (int j = 0; j < 4; ++j) {
      const float4 wq = wv[4 + j];
      acc[j*4+0] = fmaf(xs1, wq.x, acc[j*4+0]);
      acc[j*4+1] = fmaf(xs1, wq.y, acc[j*4+1]);
      acc[j*4+2] = fmaf(xs1, wq.z, acc[j*4+2]);
      acc[j*4+3] = fmaf(xs1, wq.w, acc[j*4+3]);
    }
  };
  LD(wA, 0);
  LD(wB, 2);
  xCur = ld4c(x);
  int k2 = 0;
  for (; k2 < K - 4; k2 += 4) {
    xNxt = ld4c(x + k2 + 4);
    FMA2(wA, xCur.x, xCur.y);
    LD(wA, k2 + 4);
    FMA2(wB, xCur.z, xCur.w);
    LD(wB, k2 + 6);
    xCur = xNxt;
  }
  FMA2(wA, xCur.x, xCur.y);
  FMA2(wB, xCur.z, xCur.w);
}

// head slice (8 cols): ~3% of FLOPs, simple version
template <int K, int LDW, class XT, class WT>
__device__ __forceinline__ void gemm8(float* __restrict__ acc, const XT* __restrict__ x,
                                      const WT* __restrict__ wb) {
#pragma unroll 2
  for (int k = 0; k < K; k += 4) {
    float4 xv = ld4c(x + k);
#pragma unroll
    for (int kk = 0; kk < 4; ++kk) {
      float xs = (kk == 0) ? xv.x : (kk == 1) ? xv.y : (kk == 2) ? xv.z : xv.w;
      const WT* wr = wb + (size_t)(k + kk) * LDW;
#pragma unroll
      for (int j = 0; j < 2; ++j) {
        float4 wv = ld4c(wr + j * 4);
        acc[j*4+0] = fmaf(xs, wv.x, acc[j*4+0]);
        acc[j*4+1] = fmaf(xs, wv.y, acc[j*4+1]);
        acc[j*4+2] = fmaf(xs, wv.z, acc[j*4+2]);
        acc[j*4+3] = fmaf(xs, wv.w, acc[j*4+3]);
      }
    }
  }
}

template <class WT>
__device__ __forceinline__ void ld16v(float* d, const WT* p) {
#pragma unroll
  for (int j = 0; j < 4; ++j) {
    float4 v = ld4c(p + j * 4);
    d[j*4+0] = v.x; d[j*4+1] = v.y; d[j*4+2] = v.z; d[j*4+3] = v.w;
  }
}
template <class WT>
__device__ __forceinline__ void add16v(float* d, const WT* p) {
#pragma unroll
  for (int j = 0; j < 4; ++j) {
    float4 v = ld4c(p + j * 4);
    d[j*4+0] += v.x; d[j*4+1] += v.y; d[j*4+2] += v.z; d[j*4+3] += v.w;
  }
}
__device__ __forceinline__ void st16v(float* p, const float* a) {
#pragma unroll
  for (int j = 0; j < 4; ++j)
    *(float4*)(p + j * 4) = make_float4(a[j*4+0], a[j*4+1], a[j*4+2], a[j*4+3]);
}

template <bool RELU, class WT>
__device__ __forceinline__ void ln_apply16(float* acc, float mean, float rstd,
                                           const WT* g, const WT* b) {
#pragma unroll
  for (int j = 0; j < 4; ++j) {
    float4 gv = ld4c(g + j * 4), bv = ld4c(b + j * 4);
    acc[j*4+0] = (acc[j*4+0] - mean) * rstd * gv.x + bv.x;
    acc[j*4+1] = (acc[j*4+1] - mean) * rstd * gv.y + bv.y;
    acc[j*4+2] = (acc[j*4+2] - mean) * rstd * gv.z + bv.z;
    acc[j*4+3] = (acc[j*4+3] - mean) * rstd * gv.w + bv.w;
    if (RELU) {
      acc[j*4+0] = fmaxf(acc[j*4+0], 0.f);
      acc[j*4+1] = fmaxf(acc[j*4+1], 0.f);
      acc[j*4+2] = fmaxf(acc[j*4+2], 0.f);
      acc[j*4+3] = fmaxf(acc[j*4+3], 0.f);
    }
  }
}

__device__ __forceinline__ void ln_stats16(const float* acc, int w, int l, float* red,
                                           float& mean, float& rstd) {
  float s = 0.f, q = 0.f;
#pragma unroll
  for (int j = 0; j < 16; ++j) { s += acc[j]; q += acc[j] * acc[j]; }
  __syncthreads();                       // previous red/LDS use done
  *(float2*)(red + (w * 64 + l) * 2) = make_float2(s, q);
  __syncthreads();
  s = 0.f; q = 0.f;
#pragma unroll
  for (int ww = 0; ww < 16; ++ww) {
    float2 v = *(const float2*)(red + (ww * 64 + l) * 2);
    s += v.x; q += v.y;
  }
  mean = s * (1.f / 256.f);
  float var = q * (1.f / 256.f) - mean * mean;
  rstd = rsqrtf(var + 1e-5f);
}

template <class T>
__device__ __forceinline__ void stage256(float* dst, const T* __restrict__ src, int nv, int t) {
#pragma unroll
  for (int ii = 0; ii < 4; ++ii) {
    int i = t + ii * TPB;
    int r = i >> 6, c4 = i & 63;
    float4 v = make_float4(0.f, 0.f, 0.f, 0.f);
    if (r < nv) v = ld4c(src + (size_t)r * HD + c4 * 4);
    *(float4*)(dst + r * AST + c4 * 4) = v;
  }
}

// ---------------- the fused row kernel: 64 rows/block, 16 waves x 16 cols ----------------
template <class T, class WT, int WANT>
__global__ __launch_bounds__(TPB, 4) void k_row(
    const int* __restrict__ flag, int Brows,
    const T* __restrict__ node_i, const T* __restrict__ node_j,
    const T* __restrict__ latent, const T* __restrict__ hin,
    const int* __restrict__ tok,
    const WT* __restrict__ We, const WT* __restrict__ be,
    const WT* __restrict__ ge, const WT* __restrict__ bee,
    const WT* __restrict__ gn, const WT* __restrict__ bn,
    const WT* __restrict__ emb,
    const WT* __restrict__ W_ih, const WT* __restrict__ b_ih,
    const WT* __restrict__ W_hh, const WT* __restrict__ b_hh,
    const WT* __restrict__ Wf, const WT* __restrict__ bfb,
    const WT* __restrict__ gf, const WT* __restrict__ bff,
    const WT* __restrict__ W1, const WT* __restrict__ b1,
    const WT* __restrict__ W2, const WT* __restrict__ b2,
    const float* __restrict__ Wcvo, const float* __restrict__ bcvo,
    T* __restrict__ outL, T* __restrict__ outNH) {
  if (*flag != WANT) return;
  extern __shared__ float sm[];
  float* A   = sm;                    // [64][AST]
  float* Bb  = sm + 64 * AST;         // [64][AST]  (also head-partial scratch)
  float* red = sm + 2 * 64 * AST;     // 16*64*2 = 2048 f32
  float* sc  = red + 2048;            // 512 f32 (latent stage)
  int* tokS  = (int*)(sc + 512);      // 64 ints

  const int t = threadIdx.x;
  const int w = __builtin_amdgcn_readfirstlane(t >> 6);  // wave id 0..15 (uniform)
  const int l = t & 63;                                  // lane == local row
  const int row0 = blockIdx.x * RPB;
  int nv = Brows - row0; if (nv > RPB) nv = RPB;
  const int cb = w * 16;              // this wave's output-column base

  if (t < 64) tokS[t] = (t < nv) ? tok[row0 + t] : 0;
  stage256(A, node_i + (size_t)row0 * HD, nv, t);
  __syncthreads();

  // ---- edge = relu(LN([node_i|node_j] @ We + be)) ----
  float acc[16];
  ld16v(acc, be + cb);
  gemm16<256, 256>(acc, A + l * AST, We + cb);
  __syncthreads();                    // A(node_i) reads done
  stage256(A, node_j + (size_t)row0 * HD, nv, t);
  __syncthreads();
  gemm16<256, 256>(acc, A + l * AST, We + (size_t)256 * 256 + cb);
  float mean, rstd;
  ln_stats16(acc, w, l, red, mean, rstd);
  ln_apply16<true>(acc, mean, rstd, ge + cb, bee + cb);
  st16v(Bb + l * AST + cb, acc);      // Bb = edge
  __syncthreads();

  // ---- fusion accumulator: edge part first ----
  float fac[16];
  ld16v(fac, bfb + cb);
  gemm16<256, 256>(fac, Bb + l * AST, Wf + cb);

  // ---- attended = LN(latent @ Wcvo + bcvo) ----
  if (t < 512) {
    int r = t >> 3, c = t & 7;
    sc[t] = (r < nv) ? ld(latent + (size_t)(row0 + r) * 8 + c) : 0.f;
  }
  __syncthreads();                    // sc ready; also: Bb(edge) fusion reads done
  ld16v(acc, bcvo + cb);
  gemm16<8, 256>(acc, sc + l * 8, Wcvo + cb);
  ln_stats16(acc, w, l, red, mean, rstd);
  ln_apply16<false>(acc, mean, rstd, gn + cb, bn + cb);
  st16v(A + l * AST + cb, acc);       // A = attended
  __syncthreads();

  gemm16<256, 256>(fac, A + l * AST, Wf + (size_t)256 * 256 + cb);  // fusion: att part

  stage256(Bb, hin + (size_t)row0 * HD, nv, t);                     // Bb = hin
  __syncthreads();

  const int tk = tokS[l];
  const WT* embr = emb + (size_t)tk * HD;   // 8 rows only: cache-resident

  // ---- GRU r gate ----
  ld16v(acc, b_ih + cb); add16v(acc, b_hh + cb);
  gemm16<256, 768>(acc, A + l * AST, W_ih + cb);
  gemm16<256, 768>(acc, embr, W_ih + (size_t)256 * 768 + cb);
  gemm16<256, 768>(acc, Bb + l * AST, W_hh + cb);
  float rg[16];
#pragma unroll
  for (int j = 0; j < 16; ++j) rg[j] = 1.f / (1.f + expf(-acc[j]));

  // ---- ghn; rg <- r * ghn ----
  ld16v(acc, b_hh + 512 + cb);
  gemm16<256, 768>(acc, Bb + l * AST, W_hh + 512 + cb);
#pragma unroll
  for (int j = 0; j < 16; ++j) rg[j] *= acc[j];

  // ---- gin; rg <- n = tanh(gin + r*ghn) ----
  ld16v(acc, b_ih + 512 + cb);
  gemm16<256, 768>(acc, A + l * AST, W_ih + 512 + cb);
  gemm16<256, 768>(acc, embr, W_ih + (size_t)256 * 768 + 512 + cb);
#pragma unroll
  for (int j = 0; j < 16; ++j) rg[j] = tanhf(acc[j] + rg[j]);

  // ---- z gate; newh ----
  ld16v(acc, b_ih + 256 + cb); add16v(acc, b_hh + 256 + cb);
  gemm16<256, 768>(acc, A + l * AST, W_ih + 256 + cb);
  gemm16<256, 768>(acc, embr, W_ih + (size_t)256 * 768 + 256 + cb);
  gemm16<256, 768>(acc, Bb + l * AST, W_hh + 256 + cb);
  __syncthreads();                    // all Bb(hin)/A(att) GEMM reads done
#pragma unroll
  for (int j4 = 0; j4 < 4; ++j4) {
    float4 hv = ld4c(Bb + l * AST + cb + j4 * 4);
    float z0 = 1.f / (1.f + expf(-acc[j4*4+0]));
    float z1 = 1.f / (1.f + expf(-acc[j4*4+1]));
    float z2 = 1.f / (1.f + expf(-acc[j4*4+2]));
    float z3 = 1.f / (1.f + expf(-acc[j4*4+3]));
    acc[j4*4+0] = (1.f - z0) * rg[j4*4+0] + z0 * hv.x;
    acc[j4*4+1] = (1.f - z1) * rg[j4*4+1] + z1 * hv.y;
    acc[j4*4+2] = (1.f - z2) * rg[j4*4+2] + z2 * hv.z;
    acc[j4*4+3] = (1.f - z3) * rg[j4*4+3] + z3 * hv.w;
  }
  st16v(Bb + l * AST + cb, acc);      // Bb = newh
  __syncthreads();

  for (int i = t; i < nv * HD; i += TPB) {
    int r = i >> 8, c = i & 255;
    outNH[(size_t)(row0 + r) * HD + c] = (T)Bb[r * AST + c];
  }

  // ---- fusion: newh part; fused = relu(LN(fac)) ----
  gemm16<256, 256>(fac, Bb + l * AST, Wf + (size_t)512 * 256 + cb);
  ln_stats16(fac, w, l, red, mean, rstd);
  ln_apply16<true>(fac, mean, rstd, gf + cb, bff + cb);
  st16v(A + l * AST + cb, fac);       // A = fused
  __syncthreads();

  // ---- head: relu(fused @ W1 + b1) @ W2 + b2 ----
  float h1[8];
  {
    float4 v0 = ld4c(b1 + w * 8), v1 = ld4c(b1 + w * 8 + 4);
    h1[0]=v0.x; h1[1]=v0.y; h1[2]=v0.z; h1[3]=v0.w;
    h1[4]=v1.x; h1[5]=v1.y; h1[6]=v1.z; h1[7]=v1.w;
  }
  gemm8<256, 128>(h1, A + l * AST, W1 + w * 8);
  float part[8];
#pragma unroll
  for (int o = 0; o < 8; ++o) part[o] = 0.f;
#pragma unroll
  for (int kk = 0; kk < 8; ++kk) {
    float hval = fmaxf(h1[kk], 0.f);
    const WT* w2r = W2 + (size_t)(w * 8 + kk) * 8;
    float4 a0 = ld4c(w2r), a1 = ld4c(w2r + 4);
    part[0] = fmaf(hval, a0.x, part[0]);
    part[1] = fmaf(hval, a0.y, part[1]);
    part[2] = fmaf(hval, a0.z, part[2]);
    part[3] = fmaf(hval, a0.w, part[3]);
    part[4] = fmaf(hval, a1.x, part[4]);
    part[5] = fmaf(hval, a1.y, part[5]);
    part[6] = fmaf(hval, a1.z, part[6]);
    part[7] = fmaf(hval, a1.w, part[7]);
  }
  float* hp = Bb;                     // reuse Bb for 16*64*8 partials (newh consumed)
  *(float4*)(hp + (w * 64 + l) * 8)     = make_float4(part[0], part[1], part[2], part[3]);
  *(float4*)(hp + (w * 64 + l) * 8 + 4) = make_float4(part[4], part[5], part[6], part[7]);
  __syncthreads();
  if (w == 0 && l < nv) {
#pragma unroll
    for (int o = 0; o < 8; ++o) {
      float lg = ld(b2 + o);
#pragma unroll
      for (int ww = 0; ww < 16; ++ww) lg += hp[(ww * 64 + l) * 8 + o];
      outL[(size_t)(row0 + l) * 8 + o] = (T)lg;
    }
  }
}

// ---------------- launch ----------------
extern "C" void kernel_launch(void* const* d_in, const int* in_sizes, int n_in,
                              void* d_out, int out_size, void* d_ws, size_t ws_size,
                              hipStream_t stream) {
  char* ws = (char*)d_ws;
  const int B = in_sizes[0] / HD;
  const int nblk = (B + RPB - 1) / RPB;
  int* flag = (int*)ws;
  float* tmpcv = (float*)(ws + 1024);
  float* Wcvo  = (float*)(ws + 16384);
  float* bcvo  = (float*)(ws + 24576);
  float* conv  = (float*)(ws + CONV_OFF);

  int nw = B * 128; if (nw > 16384) nw = 16384;
  k_detect<<<1, 256, 0, stream>>>((const unsigned int*)d_in[0], flag, nw);

  const size_t SMEM = (size_t)(2 * 64 * AST + 2048 + 512) * 4 + 64 * 4;

  // ---- f32 world ----
  {
    auto P = [&](int i) { return (const float*)d_in[i]; };
    k_cvo_a<float, 0><<<9, 256, 0, stream>>>(flag, P(9), P(15), P(10), P(16), tmpcv);
    k_cvo_b<float, 0><<<9, 256, 0, stream>>>(flag, tmpcv, P(17), P(18), Wcvo, bcvo);
    (void)hipFuncSetAttribute(reinterpret_cast<const void*>(&k_row<float, float, 0>),
                              hipFuncAttributeMaxDynamicSharedMemorySize, (int)SMEM);
    k_row<float, float, 0><<<nblk, TPB, SMEM, stream>>>(
        flag, B, P(0), P(1), P(2), P(3), (const int*)d_in[4],
        P(5), P(6), P(7), P(8), P(19), P(20), P(21),
        P(22), P(23), P(24), P(25), P(26), P(27), P(28), P(29),
        P(30), P(31), P(32), P(33), Wcvo, bcvo,
        (float*)d_out, (float*)d_out + (size_t)B * 8);
  }
  // ---- bf16 world ----
  {
    auto P = [&](int i) { return (const bf16*)d_in[i]; };
    k_cvo_a<bf16, 1><<<9, 256, 0, stream>>>(flag, P(9), P(15), P(10), P(16), tmpcv);
    k_cvo_b<bf16, 1><<<9, 256, 0, stream>>>(flag, tmpcv, P(17), P(18), Wcvo, bcvo);
    bf16* oL = (bf16*)d_out;
    if (ws_size >= (size_t)WS_NEED) {
      k_conv<<<512, 256, 0, stream>>>(flag,
          P(5), P(6), P(7), P(8), P(19), P(20), P(21),
          P(22), P(23), P(24), P(25), P(26), P(27), P(28), P(29),
          P(30), P(31), P(32), P(33), conv);
      const float* C = conv;
      (void)hipFuncSetAttribute(reinterpret_cast<const void*>(&k_row<bf16, float, 1>),
                                hipFuncAttributeMaxDynamicSharedMemorySize, (int)SMEM);
      k_row<bf16, float, 1><<<nblk, TPB, SMEM, stream>>>(
          flag, B, P(0), P(1), P(2), P(3), (const int*)d_in[4],
          C + 0, C + 131072, C + 131328, C + 131584, C + 131840, C + 132096, C + 132352,
          C + 134400, C + 527616, C + 528384, C + 724992, C + 725760, C + 922368,
          C + 922624, C + 922880, C + 923136, C + 955904, C + 956032, C + 957056,
          Wcvo, bcvo, oL, oL + (size_t)B * 8);
    } else {
      (void)hipFuncSetAttribute(reinterpret_cast<const void*>(&k_row<bf16, bf16, 1>),
                                hipFuncAttributeMaxDynamicSharedMemorySize, (int)SMEM);
      k_row<bf16, bf16, 1><<<nblk, TPB, SMEM, stream>>>(
          flag, B, P(0), P(1), P(2), P(3), (const int*)d_in[4],
          P(5), P(6), P(7), P(8), P(19), P(20), P(21),
          P(22), P(23), P(24), P(25), P(26), P(27), P(28), P(29),
          P(30), P(31), P(32), P(33), Wcvo, bcvo, oL, oL + (size_t)B * 8);
    }
  }
}

// Round 4
// 2237.389 us; speedup vs baseline: 1.3447x; 1.3447x over previous
//
#include <hip/hip_runtime.h>

// LatentGuidedEdgeDecoder — round 7: bf16 world -> MFMA.
// R6 post-mortem: hand-pipelined gemm16 (dynamic loop) doubled VALU issue
// (address math + reg copies): 2284 -> 3009us. Reverted to R5's compiler-
// scheduled gemm16 for the f32 world / bf16 fallback.
// R7 main change: absmax == 2^-7 every round => live data is bf16. Use
// v_mfma_f32_16x16x32_bf16 for all K>=256 GEMMs in the bf16 world:
//  * k_prep reformats weights once/call into B-fragment order in ws.
//    Safety: A and B fragments share the same k-map on CDNA; packing BOTH
//    with the same assumed map makes the contraction permutation-invariant.
//    C/D map (col=lane&15, row=(lane>>4)*4+reg) is HW-verified.
//  * k_egru precomputes E768[tok] = emb@W_ih[256:512]+b_ih (8x768) --
//    removes the emb GEMM and the 3rd LDS operand.
//  * k_mfma: 64 rows/block, 512 thr = 8 waves; wave = 2 row-tiles x 4
//    col-tiles (acc 32 f32; B-frag reuse x2). LDS 74KB -> 2 blocks/CU.
//    LN per-row in D-layout: 16-lane shfl_xor + cross-wave LDS (red).
//    K=8 attention + W2 head stay VALU (trivial FLOPs).

typedef __bf16 bf16;
typedef __attribute__((ext_vector_type(8))) short short8v;
typedef __attribute__((ext_vector_type(4))) float f32x4;

#define HD 256
#define RPB 64
#define AST 260    // f32 path LDS stride (f32 elems)
#define AST2 264   // mfma path LDS stride (bf16 elems); row = 528B, 16B-aligned
#define TPB 1024   // f32-path threads
#define TPM 512    // mfma-path threads (8 waves)

// ws layout (bf16 world): flag@0 tmpcv@1024 Wcvo@16384 bcvo@24576 E768@28672
// frag weights @65536 (bf16): We 131072 el | Wih(att rows) 196608 | Whh 196608
// | Wf 196608 | W1 32768 -> 753664 elems
#define FB_OFF 65536
#define WE_E 0
#define WIH_E 131072
#define WHH_E 327680
#define WF_E 524288
#define W1_E 720896
#define FRAG_ELEMS 753664
#define WS_NEED (FB_OFF + FRAG_ELEMS * 2)

__device__ __forceinline__ float bf2f(unsigned short u) {
  union { unsigned int i; float f; } c; c.i = ((unsigned)u) << 16; return c.f;
}
__device__ __forceinline__ float4 ld4c(const float* p) { return *(const float4*)p; }
__device__ __forceinline__ float4 ld4c(const bf16* p) {
  ushort4 u = *(const ushort4*)p;
  return make_float4(bf2f(u.x), bf2f(u.y), bf2f(u.z), bf2f(u.w));
}
template <class T>
__device__ __forceinline__ float ld(const T* __restrict__ p) { return (float)*p; }

__device__ __forceinline__ f32x4 MFMA(short8v a, short8v b, f32x4 c) {
  return __builtin_amdgcn_mfma_f32_16x16x32_bf16(a, b, c, 0, 0, 0);
}

// ---------------- dtype detector ----------------
__global__ void k_detect(const unsigned int* __restrict__ wds, int* __restrict__ flag, int nw) {
  __shared__ int sRed[4];
  int t = threadIdx.x;
  int cnt = 0;
  for (int i = t; i < nw; i += 256) {
    unsigned e = (wds[i] >> 7) & 0xFFu;
    cnt += (e >= 110u && e <= 140u) ? 1 : 0;
  }
#pragma unroll
  for (int m = 1; m < 64; m <<= 1) cnt += __shfl_xor(cnt, m);
  if ((t & 63) == 0) sRed[t >> 6] = cnt;
  __syncthreads();
  if (t == 0) flag[0] = (sRed[0] + sRed[1] + sRed[2] + sRed[3] > nw / 2) ? 1 : 0;
}

// ---------------- attention collapse precompute ----------------
template <class T, int WANT>
__global__ void k_cvo_a(const int* __restrict__ flag, const T* __restrict__ Wc,
                        const T* __restrict__ Wv, const T* __restrict__ bc,
                        const T* __restrict__ bv, float* __restrict__ tmp) {
  if (*flag != WANT) return;
  int i = blockIdx.x;
  int m = threadIdx.x;
  float s = 0.f;
  if (i < 8) {
    for (int u = 0; u < 256; ++u) s += ld(Wc + i * 256 + u) * ld(Wv + (size_t)u * 256 + m);
  } else {
    for (int u = 0; u < 256; ++u) s += ld(bc + u) * ld(Wv + (size_t)u * 256 + m);
    s += ld(bv + m);
  }
  tmp[i * 256 + m] = s;
}

template <class T, int WANT>
__global__ void k_cvo_b(const int* __restrict__ flag, const float* __restrict__ tmp,
                        const T* __restrict__ Wo, const T* __restrict__ bo,
                        float* __restrict__ Wcvo, float* __restrict__ bcvo) {
  if (*flag != WANT) return;
  int i = blockIdx.x;
  int m = threadIdx.x;
  float s = 0.f;
  const float* tr = tmp + i * 256;
  for (int u = 0; u < 256; ++u) s += tr[u] * ld(Wo + (size_t)u * 256 + m);
  if (i < 8) Wcvo[i * 256 + m] = s;
  else       bcvo[m] = s + ld(bo + m);
}

// ---------------- MFMA weight reformat (bf16 world) ----------------
// frag elem e: j=e&7, l=(e>>3)&63, tile=e>>9; kt=tile/NT, nt=tile%NT;
// value = W[kt*32 + 8*(l>>4) + j][nt*16 + (l&15)]
__global__ void k_prep(const int* __restrict__ flag,
                       const bf16* We, const bf16* Wih, const bf16* Whh,
                       const bf16* Wf, const bf16* W1, bf16* __restrict__ dst) {
  if (*flag != 1) return;
  const bf16* srcs[5] = {We, Wih, Whh, Wf, W1};
  const int Ns[5] = {256, 768, 768, 256, 128};
  const int offs[6] = {WE_E, WIH_E, WHH_E, WF_E, W1_E, FRAG_ELEMS};
  int t = blockIdx.x * blockDim.x + threadIdx.x;
  int np = gridDim.x * blockDim.x;
  for (int seg = 0; seg < 5; ++seg) {
    const bf16* s = srcs[seg];
    int N = Ns[seg], NT = N >> 4;
    bf16* d = dst + offs[seg];
    int n = offs[seg + 1] - offs[seg];
    for (int e = t; e < n; e += np) {
      int j = e & 7, lx = (e >> 3) & 63, tl = e >> 9;
      int kt = tl / NT, nt = tl - kt * NT;
      int sk = kt * 32 + ((lx >> 4) << 3) + j;
      int sn = nt * 16 + (lx & 15);
      d[e] = s[(size_t)sk * N + sn];
    }
  }
}

// E768[tok][col] = sum_k emb[tok][k]*W_ih[256+k][col] + b_ih[col]
__global__ void k_egru(const int* __restrict__ flag, const bf16* __restrict__ emb,
                       const bf16* __restrict__ Wih, const bf16* __restrict__ b_ih,
                       float* __restrict__ E) {
  if (*flag != 1) return;
  int tok = blockIdx.x, c = threadIdx.x;  // 8 x 768
  float s = ld(b_ih + c);
  for (int k = 0; k < 256; ++k)
    s += ld(emb + tok * 256 + k) * ld(Wih + (size_t)(256 + k) * 768 + c);
  E[tok * 768 + c] = s;
}

// ---------------- MFMA micro-helpers ----------------
// acc[rti][nti] over 2 row-tiles x 4 col-tiles; nKt K-chunks of 32.
__device__ __forceinline__ void mm4(f32x4 acc[2][4], const bf16* __restrict__ X,
                                    int rowBase, int ktA0, int nKt,
                                    const bf16* __restrict__ WB, int NT,
                                    int ktB0, int ntB, int lane16, int lg, int l) {
#pragma unroll 2
  for (int kt = 0; kt < nKt; ++kt) {
    const bf16* xp = X + (size_t)(rowBase + lane16) * AST2 + (ktA0 + kt) * 32 + lg * 8;
    short8v a0 = *(const short8v*)xp;
    short8v a1 = *(const short8v*)(xp + 16 * AST2);
    const bf16* wp = WB + (((size_t)(ktB0 + kt) * NT + ntB) * 64 + l) * 8;
#pragma unroll
    for (int nti = 0; nti < 4; ++nti) {
      short8v bfr = *(const short8v*)(wp + nti * 512);
      acc[0][nti] = MFMA(a0, bfr, acc[0][nti]);
      acc[1][nti] = MFMA(a1, bfr, acc[1][nti]);
    }
  }
}

__device__ __forceinline__ void mm2(f32x4 acc[2][2], const bf16* __restrict__ X,
                                    int rowBase, const bf16* __restrict__ WB,
                                    int ntB, int lane16, int lg, int l) {
#pragma unroll 2
  for (int kt = 0; kt < 8; ++kt) {
    const bf16* xp = X + (size_t)(rowBase + lane16) * AST2 + kt * 32 + lg * 8;
    short8v a0 = *(const short8v*)xp;
    short8v a1 = *(const short8v*)(xp + 16 * AST2);
    const bf16* wp = WB + (((size_t)kt * 8 + ntB) * 64 + l) * 8;
#pragma unroll
    for (int nti = 0; nti < 2; ++nti) {
      short8v bfr = *(const short8v*)(wp + nti * 512);
      acc[0][nti] = MFMA(a0, bfr, acc[0][nti]);
      acc[1][nti] = MFMA(a1, bfr, acc[1][nti]);
    }
  }
}

__device__ __forceinline__ void zero4(f32x4 acc[2][4]) {
#pragma unroll
  for (int a = 0; a < 2; ++a)
#pragma unroll
    for (int b = 0; b < 4; ++b) acc[a][b] = (f32x4){0.f, 0.f, 0.f, 0.f};
}

template <class WT>
__device__ __forceinline__ void addB4(f32x4 acc[2][4], const WT* bvec, int cg, int lane16) {
#pragma unroll
  for (int nti = 0; nti < 4; ++nti) {
    float bv = ld(bvec + (cg * 4 + nti) * 16 + lane16);
#pragma unroll
    for (int rti = 0; rti < 2; ++rti)
#pragma unroll
      for (int r = 0; r < 4; ++r) acc[rti][nti][r] += bv;
  }
}

__device__ __forceinline__ void addE4(f32x4 acc[2][4], const float* __restrict__ E768,
                                      const int* __restrict__ tokS, int gateOff,
                                      int rtp, int cg, int lane16, int lg) {
#pragma unroll
  for (int rti = 0; rti < 2; ++rti)
#pragma unroll
    for (int r = 0; r < 4; ++r) {
      int grow = (rtp * 2 + rti) * 16 + lg * 4 + r;
      const float* er = E768 + tokS[grow] * 768 + gateOff;
#pragma unroll
      for (int nti = 0; nti < 4; ++nti)
        acc[rti][nti][r] += er[(cg * 4 + nti) * 16 + lane16];
    }
}

// LN over 256 cols per row, values in D-layout. red: [64 rows][4 cg][2] f32.
template <class WT>
__device__ __forceinline__ void lnD(f32x4 acc[2][4], int rtp, int cg, int lane16, int lg,
                                    float* red, const WT* g, const WT* b, bool relu) {
  float sv[2][4], qv[2][4];
#pragma unroll
  for (int rti = 0; rti < 2; ++rti)
#pragma unroll
    for (int r = 0; r < 4; ++r) {
      float s = 0.f, q = 0.f;
#pragma unroll
      for (int nti = 0; nti < 4; ++nti) { float v = acc[rti][nti][r]; s += v; q += v * v; }
#pragma unroll
      for (int m = 1; m < 16; m <<= 1) { s += __shfl_xor(s, m); q += __shfl_xor(q, m); }
      sv[rti][r] = s; qv[rti][r] = q;
    }
  __syncthreads();                      // prior red users done (callers ensure)
  if (lane16 == 0) {
#pragma unroll
    for (int rti = 0; rti < 2; ++rti)
#pragma unroll
      for (int r = 0; r < 4; ++r) {
        int grow = (rtp * 2 + rti) * 16 + lg * 4 + r;
        red[grow * 8 + cg * 2] = sv[rti][r];
        red[grow * 8 + cg * 2 + 1] = qv[rti][r];
      }
  }
  __syncthreads();
  float gv[4], bv[4];
#pragma unroll
  for (int nti = 0; nti < 4; ++nti) {
    int gc = (cg * 4 + nti) * 16 + lane16;
    gv[nti] = ld(g + gc); bv[nti] = ld(b + gc);
  }
#pragma unroll
  for (int rti = 0; rti < 2; ++rti)
#pragma unroll
    for (int r = 0; r < 4; ++r) {
      int grow = (rtp * 2 + rti) * 16 + lg * 4 + r;
      float s = red[grow * 8 + 0] + red[grow * 8 + 2] + red[grow * 8 + 4] + red[grow * 8 + 6];
      float q = red[grow * 8 + 1] + red[grow * 8 + 3] + red[grow * 8 + 5] + red[grow * 8 + 7];
      float mean = s * (1.f / 256.f);
      float var = q * (1.f / 256.f) - mean * mean;
      float rstd = rsqrtf(var + 1e-5f);
#pragma unroll
      for (int nti = 0; nti < 4; ++nti) {
        float v = (acc[rti][nti][r] - mean) * rstd * gv[nti] + bv[nti];
        acc[rti][nti][r] = relu ? fmaxf(v, 0.f) : v;
      }
    }
}

__device__ __forceinline__ void scatD(bf16* X, const f32x4 acc[2][4], int rtp, int cg,
                                      int lane16, int lg) {
#pragma unroll
  for (int rti = 0; rti < 2; ++rti)
#pragma unroll
    for (int r = 0; r < 4; ++r) {
      int grow = (rtp * 2 + rti) * 16 + lg * 4 + r;
#pragma unroll
      for (int nti = 0; nti < 4; ++nti) {
        int gc = (cg * 4 + nti) * 16 + lane16;
        X[(size_t)grow * AST2 + gc] = (bf16)acc[rti][nti][r];
      }
    }
}

__device__ __forceinline__ void stageB(bf16* dst, const bf16* __restrict__ src,
                                       int nv, int t) {
#pragma unroll
  for (int ii = 0; ii < 4; ++ii) {
    int i = t + ii * TPM;               // 2048 chunks of 8 bf16
    int r = i >> 5, c8 = i & 31;
    uint4 v = make_uint4(0u, 0u, 0u, 0u);
    if (r < nv) v = *(const uint4*)(src + (size_t)r * HD + c8 * 8);
    *(uint4*)(dst + (size_t)r * AST2 + c8 * 8) = v;
  }
}

// ---------------- the MFMA fused kernel (bf16 world) ----------------
__global__ __launch_bounds__(TPM, 4) void k_mfma(
    const int* __restrict__ flag, int Brows,
    const bf16* __restrict__ node_i, const bf16* __restrict__ node_j,
    const bf16* __restrict__ latent, const bf16* __restrict__ hin,
    const int* __restrict__ tok,
    const bf16* __restrict__ be, const bf16* __restrict__ ge, const bf16* __restrict__ bee,
    const bf16* __restrict__ gn, const bf16* __restrict__ bn,
    const bf16* __restrict__ b_hh,
    const bf16* __restrict__ bfb, const bf16* __restrict__ gf, const bf16* __restrict__ bff,
    const bf16* __restrict__ b1, const bf16* __restrict__ W2, const bf16* __restrict__ b2,
    const bf16* __restrict__ WeF, const bf16* __restrict__ WihF,
    const bf16* __restrict__ WhhF, const bf16* __restrict__ WfF,
    const bf16* __restrict__ W1F,
    const float* __restrict__ Wcvo, const float* __restrict__ bcvo,
    const float* __restrict__ E768,
    bf16* __restrict__ outL, bf16* __restrict__ outNH) {
  if (*flag != 1) return;
  extern __shared__ char smc[];
  bf16* X1 = (bf16*)smc;                       // [64][AST2] 33792 B
  bf16* X2 = (bf16*)(smc + 33792);             // [64][AST2] 33792 B
  float* red = (float*)(smc + 67584);          // 1024 f32
  float* sc  = (float*)(smc + 71680);          // 512 f32 (latent)
  int* tokS  = (int*)(smc + 73728);            // 64 ints

  const int t = threadIdx.x;
  const int w = __builtin_amdgcn_readfirstlane(t >> 6);  // 0..7
  const int l = t & 63;
  const int lane16 = l & 15, lg = l >> 4;
  const int rtp = w & 1;                // row-tile pair: rows rtp*32..+32
  const int cg = w >> 1;                // col-group: col-tiles cg*4..+4
  const int rowBase = rtp * 32;
  const int row0 = blockIdx.x * RPB;
  int nv = Brows - row0; if (nv > RPB) nv = RPB;

  // stage: tok, latent, node_i
  if (t < 64) tokS[t] = (t < nv) ? tok[row0 + t] : 0;
  if (t < 512) sc[t] = ((t >> 3) < nv) ? ld(latent + (size_t)row0 * 8 + t) : 0.f;
  stageB(X1, node_i + (size_t)row0 * HD, nv, t);
  __syncthreads();                                                  // B1

  // ---- EDGE = relu(LN([ni|nj]@We + be)) ----
  f32x4 acc[2][4];
  zero4(acc);
  mm4(acc, X1, rowBase, 0, 8, WeF, 16, 0, cg * 4, lane16, lg, l);
  __syncthreads();                                                  // B2
  stageB(X1, node_j + (size_t)row0 * HD, nv, t);
  __syncthreads();                                                  // B3
  mm4(acc, X1, rowBase, 0, 8, WeF, 16, 8, cg * 4, lane16, lg, l);
  addB4(acc, be, cg, lane16);
  lnD(acc, rtp, cg, lane16, lg, red, ge, bee, true);                // B4,B5
  scatD(X2, acc, rtp, cg, lane16, lg);                              // X2 = edge
  __syncthreads();                                                  // B6

  // ---- fusion acc: edge part ----
  f32x4 fac[2][4];
  zero4(fac);
  mm4(fac, X2, rowBase, 0, 8, WfF, 16, 0, cg * 4, lane16, lg, l);

  // ---- attended = LN(latent@Wcvo + bcvo) (VALU, K=8) ----
  {
    float a32[32];
#pragma unroll
    for (int j4 = 0; j4 < 8; ++j4) {
      float4 v = *(const float4*)(bcvo + w * 32 + j4 * 4);
      a32[j4 * 4 + 0] = v.x; a32[j4 * 4 + 1] = v.y;
      a32[j4 * 4 + 2] = v.z; a32[j4 * 4 + 3] = v.w;
    }
#pragma unroll
    for (int k = 0; k < 8; ++k) {
      float xs = sc[l * 8 + k];
      const float* wr = Wcvo + k * 256 + w * 32;
#pragma unroll
      for (int j4 = 0; j4 < 8; ++j4) {
        float4 wv = *(const float4*)(wr + j4 * 4);
        a32[j4 * 4 + 0] = fmaf(xs, wv.x, a32[j4 * 4 + 0]);
        a32[j4 * 4 + 1] = fmaf(xs, wv.y, a32[j4 * 4 + 1]);
        a32[j4 * 4 + 2] = fmaf(xs, wv.z, a32[j4 * 4 + 2]);
        a32[j4 * 4 + 3] = fmaf(xs, wv.w, a32[j4 * 4 + 3]);
      }
    }
    float s = 0.f, q = 0.f;
#pragma unroll
    for (int j = 0; j < 32; ++j) { s += a32[j]; q += a32[j] * a32[j]; }
    __syncthreads();                                                // B7 (red free)
    red[(w * 64 + l) * 2] = s; red[(w * 64 + l) * 2 + 1] = q;
    __syncthreads();                                                // B8
    s = 0.f; q = 0.f;
#pragma unroll
    for (int ww = 0; ww < 8; ++ww) {
      s += red[(ww * 64 + l) * 2]; q += red[(ww * 64 + l) * 2 + 1];
    }
    float mean = s * (1.f / 256.f);
    float var = q * (1.f / 256.f) - mean * mean;
    float rstd = rsqrtf(var + 1e-5f);
#pragma unroll
    for (int j = 0; j < 32; j += 2) {
      float v0 = (a32[j] - mean) * rstd * ld(gn + w * 32 + j) + ld(bn + w * 32 + j);
      float v1 = (a32[j + 1] - mean) * rstd * ld(gn + w * 32 + j + 1) + ld(bn + w * 32 + j + 1);
      bf16 pp[2] = {(bf16)v0, (bf16)v1};
      *(unsigned int*)(X1 + (size_t)l * AST2 + w * 32 + j) = *(unsigned int*)pp;
    }
  }
  __syncthreads();                                                  // B9: X1 = attended

  // ---- fusion: att part; stage hin ----
  mm4(fac, X1, rowBase, 0, 8, WfF, 16, 8, cg * 4, lane16, lg, l);
  stageB(X2, hin + (size_t)row0 * HD, nv, t);
  __syncthreads();                                                  // B10: X2 = hin

  // ---- GRU ----
  f32x4 ghn[2][4];
  zero4(ghn);
  mm4(ghn, X2, rowBase, 0, 8, WhhF, 48, 0, 32 + cg * 4, lane16, lg, l);
  addB4(ghn, b_hh + 512, cg, lane16);

  zero4(acc);  // acc_r
  mm4(acc, X1, rowBase, 0, 8, WihF, 48, 0, cg * 4, lane16, lg, l);
  mm4(acc, X2, rowBase, 0, 8, WhhF, 48, 0, cg * 4, lane16, lg, l);
  addE4(acc, E768, tokS, 0, rtp, cg, lane16, lg);
  addB4(acc, b_hh, cg, lane16);
#pragma unroll
  for (int a = 0; a < 2; ++a)
#pragma unroll
    for (int b = 0; b < 4; ++b)
#pragma unroll
      for (int r = 0; r < 4; ++r) {
        float rr = 1.f / (1.f + expf(-acc[a][b][r]));
        acc[a][b][r] = rr * ghn[a][b][r];       // acc = r * ghn
      }

  zero4(ghn);  // reuse as acc_n (gi_n)
  mm4(ghn, X1, rowBase, 0, 8, WihF, 48, 0, 32 + cg * 4, lane16, lg, l);
  addE4(ghn, E768, tokS, 512, rtp, cg, lane16, lg);
#pragma unroll
  for (int a = 0; a < 2; ++a)
#pragma unroll
    for (int b = 0; b < 4; ++b)
#pragma unroll
      for (int r = 0; r < 4; ++r)
        ghn[a][b][r] = tanhf(ghn[a][b][r] + acc[a][b][r]);  // ghn = n

  zero4(acc);  // acc_z
  mm4(acc, X1, rowBase, 0, 8, WihF, 48, 0, 16 + cg * 4, lane16, lg, l);
  mm4(acc, X2, rowBase, 0, 8, WhhF, 48, 0, 16 + cg * 4, lane16, lg, l);
  addE4(acc, E768, tokS, 256, rtp, cg, lane16, lg);
  addB4(acc, b_hh + 256, cg, lane16);
#pragma unroll
  for (int a = 0; a < 2; ++a)
#pragma unroll
    for (int r = 0; r < 4; ++r) {
      int grow = (rtp * 2 + a) * 16 + lg * 4 + r;
#pragma unroll
      for (int b = 0; b < 4; ++b) {
        int gc = (cg * 4 + b) * 16 + lane16;
        float zz = 1.f / (1.f + expf(-acc[a][b][r]));
        float hvv = (float)X2[(size_t)grow * AST2 + gc];
        acc[a][b][r] = (1.f - zz) * ghn[a][b][r] + zz * hvv;  // acc = newh
      }
    }
  __syncthreads();                                                  // B11
  scatD(X1, acc, rtp, cg, lane16, lg);                              // X1 = newh
  __syncthreads();                                                  // B12

  // outNH coalesced from X1
#pragma unroll
  for (int ii = 0; ii < 4; ++ii) {
    int i = t + ii * TPM;
    int r = i >> 5, c8 = i & 31;
    if (r < nv) {
      uint4 v = *(const uint4*)(X1 + (size_t)r * AST2 + c8 * 8);
      *(uint4*)(outNH + (size_t)(row0 + r) * HD + c8 * 8) = v;
    }
  }

  // ---- fusion: newh part; fused = relu(LN(fac + bfb)) ----
  mm4(fac, X1, rowBase, 0, 8, WfF, 16, 16, cg * 4, lane16, lg, l);
  addB4(fac, bfb, cg, lane16);
  lnD(fac, rtp, cg, lane16, lg, red, gf, bff, true);                // B13,B14
  scatD(X2, fac, rtp, cg, lane16, lg);                              // X2 = fused
  __syncthreads();                                                  // B15

  // ---- head: h1 = relu(fused@W1 + b1) ----
  f32x4 acc1[2][2];
#pragma unroll
  for (int a = 0; a < 2; ++a)
#pragma unroll
    for (int b = 0; b < 2; ++b) acc1[a][b] = (f32x4){0.f, 0.f, 0.f, 0.f};
  mm2(acc1, X2, rowBase, W1F, cg * 2, lane16, lg, l);
  float* H = (float*)X1;               // [64][132] f32 (over X1; newh consumed)
#pragma unroll
  for (int a = 0; a < 2; ++a)
#pragma unroll
    for (int r = 0; r < 4; ++r) {
      int grow = (rtp * 2 + a) * 16 + lg * 4 + r;
#pragma unroll
      for (int b = 0; b < 2; ++b) {
        int gc1 = (cg * 2 + b) * 16 + lane16;
        H[grow * 132 + gc1] = fmaxf(acc1[a][b][r] + ld(b1 + gc1), 0.f);
      }
    }
  __syncthreads();                                                  // B16

  // ---- logits = h1@W2 + b2 (split-K over 8 waves) ----
  {
    int rr = t & 63, ks = w * 16;
    float p[8];
#pragma unroll
    for (int o = 0; o < 8; ++o) p[o] = 0.f;
    for (int k = 0; k < 16; ++k) {
      float hv = H[rr * 132 + ks + k];
      const bf16* w2r = W2 + (size_t)(ks + k) * 8;
#pragma unroll
      for (int o = 0; o < 8; ++o) p[o] = fmaf(hv, ld(w2r + o), p[o]);
    }
    float* hp = (float*)X2;            // [8][64][8] f32 (fused consumed)
#pragma unroll
    for (int o = 0; o < 8; ++o) hp[(w * 64 + rr) * 8 + o] = p[o];
  }
  __syncthreads();                                                  // B17
  if (t < 64 && t < nv) {
    const float* hp = (const float*)X2;
    bf16 o8[8];
#pragma unroll
    for (int o = 0; o < 8; ++o) {
      float s = ld(b2 + o);
#pragma unroll
      for (int ww = 0; ww < 8; ++ww) s += hp[(ww * 64 + t) * 8 + o];
      o8[o] = (bf16)s;
    }
    *(uint4*)(outL + (size_t)(row0 + t) * 8) = *(uint4*)o8;
  }
}

// ================= f32-world / fallback path (R5, verified) =================
template <int K, int LDW, class XT, class WT>
__device__ __forceinline__ void gemm16(float* __restrict__ acc, const XT* __restrict__ x,
                                       const WT* __restrict__ wb) {
#pragma unroll 2
  for (int k = 0; k < K; k += 4) {
    float4 xv = ld4c(x + k);
#pragma unroll
    for (int kk = 0; kk < 4; ++kk) {
      float xs = (kk == 0) ? xv.x : (kk == 1) ? xv.y : (kk == 2) ? xv.z : xv.w;
      const WT* wr = wb + (size_t)(k + kk) * LDW;
#pragma unroll
      for (int j = 0; j < 4; ++j) {
        float4 wv = ld4c(wr + j * 4);
        acc[j*4+0] = fmaf(xs, wv.x, acc[j*4+0]);
        acc[j*4+1] = fmaf(xs, wv.y, acc[j*4+1]);
        acc[j*4+2] = fmaf(xs, wv.z, acc[j*4+2]);
        acc[j*4+3] = fmaf(xs, wv.w, acc[j*4+3]);
      }
    }
  }
}

template <int K, int LDW, class XT, class WT>
__device__ __forceinline__ void gemm8(float* __restrict__ acc, const XT* __restrict__ x,
                                      const WT* __restrict__ wb) {
#pragma unroll 2
  for (int k = 0; k < K; k += 4) {
    float4 xv = ld4c(x + k);
#pragma unroll
    for (int kk = 0; kk < 4; ++kk) {
      float xs = (kk == 0) ? xv.x : (kk == 1) ? xv.y : (kk == 2) ? xv.z : xv.w;
      const WT* wr = wb + (size_t)(k + kk) * LDW;
#pragma unroll
      for (int j = 0; j < 2; ++j) {
        float4 wv = ld4c(wr + j * 4);
        acc[j*4+0] = fmaf(xs, wv.x, acc[j*4+0]);
        acc[j*4+1] = fmaf(xs, wv.y, acc[j*4+1]);
        acc[j*4+2] = fmaf(xs, wv.z, acc[j*4+2]);
        acc[j*4+3] = fmaf(xs, wv.w, acc[j*4+3]);
      }
    }
  }
}

template <class WT>
__device__ __forceinline__ void ld16v(float* d, const WT* p) {
#pragma unroll
  for (int j = 0; j < 4; ++j) {
    float4 v = ld4c(p + j * 4);
    d[j*4+0] = v.x; d[j*4+1] = v.y; d[j*4+2] = v.z; d[j*4+3] = v.w;
  }
}
template <class WT>
__device__ __forceinline__ void add16v(float* d, const WT* p) {
#pragma unroll
  for (int j = 0; j < 4; ++j) {
    float4 v = ld4c(p + j * 4);
    d[j*4+0] += v.x; d[j*4+1] += v.y; d[j*4+2] += v.z; d[j*4+3] += v.w;
  }
}
__device__ __forceinline__ void st16v(float* p, const float* a) {
#pragma unroll
  for (int j = 0; j < 4; ++j)
    *(float4*)(p + j * 4) = make_float4(a[j*4+0], a[j*4+1], a[j*4+2], a[j*4+3]);
}

template <bool RELU, class WT>
__device__ __forceinline__ void ln_apply16(float* acc, float mean, float rstd,
                                           const WT* g, const WT* b) {
#pragma unroll
  for (int j = 0; j < 4; ++j) {
    float4 gv = ld4c(g + j * 4), bv = ld4c(b + j * 4);
    acc[j*4+0] = (acc[j*4+0] - mean) * rstd * gv.x + bv.x;
    acc[j*4+1] = (acc[j*4+1] - mean) * rstd * gv.y + bv.y;
    acc[j*4+2] = (acc[j*4+2] - mean) * rstd * gv.z + bv.z;
    acc[j*4+3] = (acc[j*4+3] - mean) * rstd * gv.w + bv.w;
    if (RELU) {
      acc[j*4+0] = fmaxf(acc[j*4+0], 0.f);
      acc[j*4+1] = fmaxf(acc[j*4+1], 0.f);
      acc[j*4+2] = fmaxf(acc[j*4+2], 0.f);
      acc[j*4+3] = fmaxf(acc[j*4+3], 0.f);
    }
  }
}

__device__ __forceinline__ void ln_stats16(const float* acc, int w, int l, float* red,
                                           float& mean, float& rstd) {
  float s = 0.f, q = 0.f;
#pragma unroll
  for (int j = 0; j < 16; ++j) { s += acc[j]; q += acc[j] * acc[j]; }
  __syncthreads();
  *(float2*)(red + (w * 64 + l) * 2) = make_float2(s, q);
  __syncthreads();
  s = 0.f; q = 0.f;
#pragma unroll
  for (int ww = 0; ww < 16; ++ww) {
    float2 v = *(const float2*)(red + (ww * 64 + l) * 2);
    s += v.x; q += v.y;
  }
  mean = s * (1.f / 256.f);
  float var = q * (1.f / 256.f) - mean * mean;
  rstd = rsqrtf(var + 1e-5f);
}

template <class T>
__device__ __forceinline__ void stage256(float* dst, const T* __restrict__ src, int nv, int t) {
#pragma unroll
  for (int ii = 0; ii < 4; ++ii) {
    int i = t + ii * TPB;
    int r = i >> 6, c4 = i & 63;
    float4 v = make_float4(0.f, 0.f, 0.f, 0.f);
    if (r < nv) v = ld4c(src + (size_t)r * HD + c4 * 4);
    *(float4*)(dst + r * AST + c4 * 4) = v;
  }
}

template <class T, class WT, int WANT>
__global__ __launch_bounds__(TPB, 4) void k_row(
    const int* __restrict__ flag, int Brows,
    const T* __restrict__ node_i, const T* __restrict__ node_j,
    const T* __restrict__ latent, const T* __restrict__ hin,
    const int* __restrict__ tok,
    const WT* __restrict__ We, const WT* __restrict__ be,
    const WT* __restrict__ ge, const WT* __restrict__ bee,
    const WT* __restrict__ gn, const WT* __restrict__ bn,
    const WT* __restrict__ emb,
    const WT* __restrict__ W_ih, const WT* __restrict__ b_ih,
    const WT* __restrict__ W_hh, const WT* __restrict__ b_hh,
    const WT* __restrict__ Wf, const WT* __restrict__ bfb,
    const WT* __restrict__ gf, const WT* __restrict__ bff,
    const WT* __restrict__ W1, const WT* __restrict__ b1,
    const WT* __restrict__ W2, const WT* __restrict__ b2,
    const float* __restrict__ Wcvo, const float* __restrict__ bcvo,
    T* __restrict__ outL, T* __restrict__ outNH) {
  if (*flag != WANT) return;
  extern __shared__ float sm[];
  float* A   = sm;
  float* Bb  = sm + 64 * AST;
  float* red = sm + 2 * 64 * AST;
  float* sc  = red + 2048;
  int* tokS  = (int*)(sc + 512);

  const int t = threadIdx.x;
  const int w = __builtin_amdgcn_readfirstlane(t >> 6);
  const int l = t & 63;
  const int row0 = blockIdx.x * RPB;
  int nv = Brows - row0; if (nv > RPB) nv = RPB;
  const int cb = w * 16;

  if (t < 64) tokS[t] = (t < nv) ? tok[row0 + t] : 0;
  stage256(A, node_i + (size_t)row0 * HD, nv, t);
  __syncthreads();

  float acc[16];
  ld16v(acc, be + cb);
  gemm16<256, 256>(acc, A + l * AST, We + cb);
  __syncthreads();
  stage256(A, node_j + (size_t)row0 * HD, nv, t);
  __syncthreads();
  gemm16<256, 256>(acc, A + l * AST, We + (size_t)256 * 256 + cb);
  float mean, rstd;
  ln_stats16(acc, w, l, red, mean, rstd);
  ln_apply16<true>(acc, mean, rstd, ge + cb, bee + cb);
  st16v(Bb + l * AST + cb, acc);
  __syncthreads();

  float fac[16];
  ld16v(fac, bfb + cb);
  gemm16<256, 256>(fac, Bb + l * AST, Wf + cb);

  if (t < 512) {
    int r = t >> 3;
    sc[t] = (r < nv) ? ld(latent + (size_t)row0 * 8 + t) : 0.f;
  }
  __syncthreads();
  ld16v(acc, bcvo + cb);
  gemm16<8, 256>(acc, sc + l * 8, Wcvo + cb);
  ln_stats16(acc, w, l, red, mean, rstd);
  ln_apply16<false>(acc, mean, rstd, gn + cb, bn + cb);
  st16v(A + l * AST + cb, acc);
  __syncthreads();

  gemm16<256, 256>(fac, A + l * AST, Wf + (size_t)256 * 256 + cb);
  stage256(Bb, hin + (size_t)row0 * HD, nv, t);
  __syncthreads();

  const int tk = tokS[l];
  const WT* embr = emb + (size_t)tk * HD;

  ld16v(acc, b_ih + cb); add16v(acc, b_hh + cb);
  gemm16<256, 768>(acc, A + l * AST, W_ih + cb);
  gemm16<256, 768>(acc, embr, W_ih + (size_t)256 * 768 + cb);
  gemm16<256, 768>(acc, Bb + l * AST, W_hh + cb);
  float rg[16];
#pragma unroll
  for (int j = 0; j < 16; ++j) rg[j] = 1.f / (1.f + expf(-acc[j]));

  ld16v(acc, b_hh + 512 + cb);
  gemm16<256, 768>(acc, Bb + l * AST, W_hh + 512 + cb);
#pragma unroll
  for (int j = 0; j < 16; ++j) rg[j] *= acc[j];

  ld16v(acc, b_ih + 512 + cb);
  gemm16<256, 768>(acc, A + l * AST, W_ih + 512 + cb);
  gemm16<256, 768>(acc, embr, W_ih + (size_t)256 * 768 + 512 + cb);
#pragma unroll
  for (int j = 0; j < 16; ++j) rg[j] = tanhf(acc[j] + rg[j]);

  ld16v(acc, b_ih + 256 + cb); add16v(acc, b_hh + 256 + cb);
  gemm16<256, 768>(acc, A + l * AST, W_ih + 256 + cb);
  gemm16<256, 768>(acc, embr, W_ih + (size_t)256 * 768 + 256 + cb);
  gemm16<256, 768>(acc, Bb + l * AST, W_hh + 256 + cb);
  __syncthreads();
#pragma unroll
  for (int j4 = 0; j4 < 4; ++j4) {
    float4 hv = ld4c(Bb + l * AST + cb + j4 * 4);
    float z0 = 1.f / (1.f + expf(-acc[j4*4+0]));
    float z1 = 1.f / (1.f + expf(-acc[j4*4+1]));
    float z2 = 1.f / (1.f + expf(-acc[j4*4+2]));
    float z3 = 1.f / (1.f + expf(-acc[j4*4+3]));
    acc[j4*4+0] = (1.f - z0) * rg[j4*4+0] + z0 * hv.x;
    acc[j4*4+1] = (1.f - z1) * rg[j4*4+1] + z1 * hv.y;
    acc[j4*4+2] = (1.f - z2) * rg[j4*4+2] + z2 * hv.z;
    acc[j4*4+3] = (1.f - z3) * rg[j4*4+3] + z3 * hv.w;
  }
  st16v(Bb + l * AST + cb, acc);
  __syncthreads();

  for (int i = t; i < nv * HD; i += TPB) {
    int r = i >> 8, c = i & 255;
    outNH[(size_t)(row0 + r) * HD + c] = (T)Bb[r * AST + c];
  }

  gemm16<256, 256>(fac, Bb + l * AST, Wf + (size_t)512 * 256 + cb);
  ln_stats16(fac, w, l, red, mean, rstd);
  ln_apply16<true>(fac, mean, rstd, gf + cb, bff + cb);
  st16v(A + l * AST + cb, fac);
  __syncthreads();

  float h1[8];
  {
    float4 v0 = ld4c(b1 + w * 8), v1 = ld4c(b1 + w * 8 + 4);
    h1[0]=v0.x; h1[1]=v0.y; h1[2]=v0.z; h1[3]=v0.w;
    h1[4]=v1.x; h1[5]=v1.y; h1[6]=v1.z; h1[7]=v1.w;
  }
  gemm8<256, 128>(h1, A + l * AST, W1 + w * 8);
  float part[8];
#pragma unroll
  for (int o = 0; o < 8; ++o) part[o] = 0.f;
#pragma unroll
  for (int kk = 0; kk < 8; ++kk) {
    float hval = fmaxf(h1[kk], 0.f);
    const WT* w2r = W2 + (size_t)(w * 8 + kk) * 8;
    float4 a0 = ld4c(w2r), a1 = ld4c(w2r + 4);
    part[0] = fmaf(hval, a0.x, part[0]);
    part[1] = fmaf(hval, a0.y, part[1]);
    part[2] = fmaf(hval, a0.z, part[2]);
    part[3] = fmaf(hval, a0.w, part[3]);
    part[4] = fmaf(hval, a1.x, part[4]);
    part[5] = fmaf(hval, a1.y, part[5]);
    part[6] = fmaf(hval, a1.z, part[6]);
    part[7] = fmaf(hval, a1.w, part[7]);
  }
  float* hp = Bb;
  *(float4*)(hp + (w * 64 + l) * 8)     = make_float4(part[0], part[1], part[2], part[3]);
  *(float4*)(hp + (w * 64 + l) * 8 + 4) = make_float4(part[4], part[5], part[6], part[7]);
  __syncthreads();
  if (w == 0 && l < nv) {
#pragma unroll
    for (int o = 0; o < 8; ++o) {
      float lg = ld(b2 + o);
#pragma unroll
      for (int ww = 0; ww < 16; ++ww) lg += hp[(ww * 64 + l) * 8 + o];
      outL[(size_t)(row0 + l) * 8 + o] = (T)lg;
    }
  }
}

// ---------------- launch ----------------
extern "C" void kernel_launch(void* const* d_in, const int* in_sizes, int n_in,
                              void* d_out, int out_size, void* d_ws, size_t ws_size,
                              hipStream_t stream) {
  char* ws = (char*)d_ws;
  const int B = in_sizes[0] / HD;
  const int nblk = (B + RPB - 1) / RPB;
  int* flag = (int*)ws;
  float* tmpcv = (float*)(ws + 1024);
  float* Wcvo  = (float*)(ws + 16384);
  float* bcvo  = (float*)(ws + 24576);
  float* E768  = (float*)(ws + 28672);
  bf16*  fragW = (bf16*)(ws + FB_OFF);

  int nw = B * 128; if (nw > 16384) nw = 16384;
  k_detect<<<1, 256, 0, stream>>>((const unsigned int*)d_in[0], flag, nw);

  const size_t SMEM_F = (size_t)(2 * 64 * AST + 2048 + 512) * 4 + 64 * 4;
  const size_t SMEM_M = 73984;

  // ---- f32 world (R5 path, verified) ----
  {
    auto P = [&](int i) { return (const float*)d_in[i]; };
    k_cvo_a<float, 0><<<9, 256, 0, stream>>>(flag, P(9), P(15), P(10), P(16), tmpcv);
    k_cvo_b<float, 0><<<9, 256, 0, stream>>>(flag, tmpcv, P(17), P(18), Wcvo, bcvo);
    (void)hipFuncSetAttribute(reinterpret_cast<const void*>(&k_row<float, float, 0>),
                              hipFuncAttributeMaxDynamicSharedMemorySize, (int)SMEM_F);
    k_row<float, float, 0><<<nblk, TPB, SMEM_F, stream>>>(
        flag, B, P(0), P(1), P(2), P(3), (const int*)d_in[4],
        P(5), P(6), P(7), P(8), P(19), P(20), P(21),
        P(22), P(23), P(24), P(25), P(26), P(27), P(28), P(29),
        P(30), P(31), P(32), P(33), Wcvo, bcvo,
        (float*)d_out, (float*)d_out + (size_t)B * 8);
  }
  // ---- bf16 world ----
  {
    auto P = [&](int i) { return (const bf16*)d_in[i]; };
    k_cvo_a<bf16, 1><<<9, 256, 0, stream>>>(flag, P(9), P(15), P(10), P(16), tmpcv);
    k_cvo_b<bf16, 1><<<9, 256, 0, stream>>>(flag, tmpcv, P(17), P(18), Wcvo, bcvo);
    bf16* oL = (bf16*)d_out;
    if (ws_size >= (size_t)WS_NEED) {
      k_prep<<<512, 256, 0, stream>>>(flag, P(5), P(22), P(24), P(26), P(30), fragW);
      k_egru<<<8, 768, 0, stream>>>(flag, P(21), P(22), P(23), E768);
      (void)hipFuncSetAttribute(reinterpret_cast<const void*>(&k_mfma),
                                hipFuncAttributeMaxDynamicSharedMemorySize, (int)SMEM_M);
      k_mfma<<<nblk, TPM, SMEM_M, stream>>>(
          flag, B, P(0), P(1), P(2), P(3), (const int*)d_in[4],
          P(6), P(7), P(8),                 // be, ge, bee
          P(19), P(20),                     // gn, bn
          P(25),                            // b_hh
          P(27), P(28), P(29),              // bfb, gf, bff
          P(31), P(32), P(33),              // b1, W2, b2
          fragW + WE_E, fragW + WIH_E, fragW + WHH_E, fragW + WF_E, fragW + W1_E,
          Wcvo, bcvo, E768,
          oL, oL + (size_t)B * 8);
    } else {
      (void)hipFuncSetAttribute(reinterpret_cast<const void*>(&k_row<bf16, bf16, 1>),
                                hipFuncAttributeMaxDynamicSharedMemorySize, (int)SMEM_F);
      k_row<bf16, bf16, 1><<<nblk, TPB, SMEM_F, stream>>>(
          flag, B, P(0), P(1), P(2), P(3), (const int*)d_in[4],
          P(5), P(6), P(7), P(8), P(19), P(20), P(21),
          P(22), P(23), P(24), P(25), P(26), P(27), P(28), P(29),
          P(30), P(31), P(32), P(33), Wcvo, bcvo, oL, oL + (size_t)B * 8);
    }
  }
}

// Round 5
// 666.645 us; speedup vs baseline: 4.5132x; 3.3562x over previous
//
#include <hip/hip_runtime.h>

// LatentGuidedEdgeDecoder — round 8: f32 world -> f16 MFMA.
// R7 post-mortem: top-5 dispatches = k_row@1024thr/VGPR48 = the f32 path; flag=0.
// FETCH 204MB = 3x67MB f32 activations. Live data is FP32 — R7's bf16 MFMA path
// was dead code. f32 VALU path floor ~1000us (no fp32 MFMA) => cast GEMM operands
// to f16 and use v_mfma_f32_16x16x32_f16 (f32 accum):
//  * f16 rel err 2^-11; with weight scale 0.02 and K<=768, output err ~1e-3
//    vs current 0.0078 absmax floor. LN/gates/blends stay f32; z*h and outNH
//    use exact f32 hin from global.
//  * k_prep: one-time f32->f16 weight reformat into B-fragment order in ws
//    (A/B share the k-map => packing both with the same map is permutation-safe).
//  * k_egru: E768[tok] = emb@W_ih[256:512]+b_ih in f32 (exact; kills emb GEMM).
//  * k_mfma: 64 rows/block, 512thr=8 waves (2 row-halves x 4 col-quarters),
//    LDS 74KB -> 2 blocks/CU = 4 waves/SIMD. LN in D-layout via 16-lane shfl
//    + cross-wave LDS. K=8 attention + W2 head stay VALU.
// bf16 world: R5-structure k_row<bf16,bf16,1> fallback (never live so far).

typedef __bf16 bf16;
typedef _Float16 f16;
typedef __attribute__((ext_vector_type(8))) _Float16 f16x8;
typedef __attribute__((ext_vector_type(4))) float f32x4;

#define HD 256
#define RPB 64
#define AST 260    // f32 fallback LDS stride (f32 elems)
#define AST2 264   // mfma LDS stride (f16 elems); row 528B, 16B-aligned
#define TPB 1024   // fallback threads
#define TPM 512    // mfma threads (8 waves)

// ws: flag@0 tmpcv@1024 Wcvo@16384 bcvo@24576 E768@28672(24576B) frag@65536
#define FB_OFF 65536
#define WE_E 0
#define WIH_E 131072
#define WHH_E 327680
#define WF_E 524288
#define W1_E 720896
#define FRAG_ELEMS 753664
#define WS_NEED (FB_OFF + FRAG_ELEMS * 2)

__device__ __forceinline__ float bf2f(unsigned short u) {
  union { unsigned int i; float f; } c; c.i = ((unsigned)u) << 16; return c.f;
}
__device__ __forceinline__ float4 ld4c(const float* p) { return *(const float4*)p; }
__device__ __forceinline__ float4 ld4c(const bf16* p) {
  ushort4 u = *(const ushort4*)p;
  return make_float4(bf2f(u.x), bf2f(u.y), bf2f(u.z), bf2f(u.w));
}
template <class T>
__device__ __forceinline__ float ld(const T* __restrict__ p) { return (float)*p; }

__device__ __forceinline__ f32x4 MFMA16(f16x8 a, f16x8 b, f32x4 c) {
  return __builtin_amdgcn_mfma_f32_16x16x32_f16(a, b, c, 0, 0, 0);
}

// ---------------- dtype detector ----------------
__global__ void k_detect(const unsigned int* __restrict__ wds, int* __restrict__ flag, int nw) {
  __shared__ int sRed[4];
  int t = threadIdx.x;
  int cnt = 0;
  for (int i = t; i < nw; i += 256) {
    unsigned e = (wds[i] >> 7) & 0xFFu;
    cnt += (e >= 110u && e <= 140u) ? 1 : 0;
  }
#pragma unroll
  for (int m = 1; m < 64; m <<= 1) cnt += __shfl_xor(cnt, m);
  if ((t & 63) == 0) sRed[t >> 6] = cnt;
  __syncthreads();
  if (t == 0) flag[0] = (sRed[0] + sRed[1] + sRed[2] + sRed[3] > nw / 2) ? 1 : 0;
}

// ---------------- attention collapse precompute ----------------
template <class T, int WANT>
__global__ void k_cvo_a(const int* __restrict__ flag, const T* __restrict__ Wc,
                        const T* __restrict__ Wv, const T* __restrict__ bc,
                        const T* __restrict__ bv, float* __restrict__ tmp) {
  if (*flag != WANT) return;
  int i = blockIdx.x;
  int m = threadIdx.x;
  float s = 0.f;
  if (i < 8) {
    for (int u = 0; u < 256; ++u) s += ld(Wc + i * 256 + u) * ld(Wv + (size_t)u * 256 + m);
  } else {
    for (int u = 0; u < 256; ++u) s += ld(bc + u) * ld(Wv + (size_t)u * 256 + m);
    s += ld(bv + m);
  }
  tmp[i * 256 + m] = s;
}

template <class T, int WANT>
__global__ void k_cvo_b(const int* __restrict__ flag, const float* __restrict__ tmp,
                        const T* __restrict__ Wo, const T* __restrict__ bo,
                        float* __restrict__ Wcvo, float* __restrict__ bcvo) {
  if (*flag != WANT) return;
  int i = blockIdx.x;
  int m = threadIdx.x;
  float s = 0.f;
  const float* tr = tmp + i * 256;
  for (int u = 0; u < 256; ++u) s += tr[u] * ld(Wo + (size_t)u * 256 + m);
  if (i < 8) Wcvo[i * 256 + m] = s;
  else       bcvo[m] = s + ld(bo + m);
}

// ---------------- f32 -> f16 fragment reformat (flag==0 world) ----------------
// frag elem e: j=e&7, lx=(e>>3)&63, tile=e>>9; kt=tile/NT, nt=tile%NT;
// value = W[kt*32 + 8*(lx>>4) + j][nt*16 + (lx&15)]
__global__ void k_prep(const int* __restrict__ flag,
                       const float* We, const float* Wih, const float* Whh,
                       const float* Wf, const float* W1, f16* __restrict__ dst) {
  if (*flag != 0) return;
  const float* srcs[5] = {We, Wih, Whh, Wf, W1};
  const int Ns[5] = {256, 768, 768, 256, 128};
  const int offs[6] = {WE_E, WIH_E, WHH_E, WF_E, W1_E, FRAG_ELEMS};
  int t = blockIdx.x * blockDim.x + threadIdx.x;
  int np = gridDim.x * blockDim.x;
  for (int seg = 0; seg < 5; ++seg) {
    const float* s = srcs[seg];
    int N = Ns[seg], NT = N >> 4;
    f16* d = dst + offs[seg];
    int n = offs[seg + 1] - offs[seg];
    for (int e = t; e < n; e += np) {
      int j = e & 7, lx = (e >> 3) & 63, tl = e >> 9;
      int kt = tl / NT, nt = tl - kt * NT;
      int sk = kt * 32 + ((lx >> 4) << 3) + j;
      int sn = nt * 16 + (lx & 15);
      d[e] = (f16)s[(size_t)sk * N + sn];
    }
  }
}

// E768[tok][c] = sum_k emb[tok][k]*W_ih[256+k][c] + b_ih[c]  (f32 exact)
__global__ void k_egru(const int* __restrict__ flag, const float* __restrict__ emb,
                       const float* __restrict__ Wih, const float* __restrict__ b_ih,
                       float* __restrict__ E) {
  if (*flag != 0) return;
  int tok = blockIdx.x, c = threadIdx.x;  // 8 x 768
  float s = b_ih[c];
  for (int k = 0; k < 256; ++k)
    s += emb[tok * 256 + k] * Wih[(size_t)(256 + k) * 768 + c];
  E[tok * 768 + c] = s;
}

// ---------------- MFMA micro-helpers ----------------
__device__ __forceinline__ void mm4(f32x4 acc[2][4], const f16* __restrict__ X,
                                    int rowBase, int ktA0, int nKt,
                                    const f16* __restrict__ WB, int NT,
                                    int ktB0, int ntB, int lane16, int lg, int l) {
#pragma unroll 2
  for (int kt = 0; kt < nKt; ++kt) {
    const f16* xp = X + (size_t)(rowBase + lane16) * AST2 + (ktA0 + kt) * 32 + lg * 8;
    f16x8 a0 = *(const f16x8*)xp;
    f16x8 a1 = *(const f16x8*)(xp + 16 * AST2);
    const f16* wp = WB + (((size_t)(ktB0 + kt) * NT + ntB) * 64 + l) * 8;
#pragma unroll
    for (int nti = 0; nti < 4; ++nti) {
      f16x8 bfr = *(const f16x8*)(wp + nti * 512);
      acc[0][nti] = MFMA16(a0, bfr, acc[0][nti]);
      acc[1][nti] = MFMA16(a1, bfr, acc[1][nti]);
    }
  }
}

__device__ __forceinline__ void mm2(f32x4 acc[2][2], const f16* __restrict__ X,
                                    int rowBase, const f16* __restrict__ WB,
                                    int ntB, int lane16, int lg, int l) {
#pragma unroll 2
  for (int kt = 0; kt < 8; ++kt) {
    const f16* xp = X + (size_t)(rowBase + lane16) * AST2 + kt * 32 + lg * 8;
    f16x8 a0 = *(const f16x8*)xp;
    f16x8 a1 = *(const f16x8*)(xp + 16 * AST2);
    const f16* wp = WB + (((size_t)kt * 8 + ntB) * 64 + l) * 8;
#pragma unroll
    for (int nti = 0; nti < 2; ++nti) {
      f16x8 bfr = *(const f16x8*)(wp + nti * 512);
      acc[0][nti] = MFMA16(a0, bfr, acc[0][nti]);
      acc[1][nti] = MFMA16(a1, bfr, acc[1][nti]);
    }
  }
}

__device__ __forceinline__ void zero4(f32x4 acc[2][4]) {
#pragma unroll
  for (int a = 0; a < 2; ++a)
#pragma unroll
    for (int b = 0; b < 4; ++b) acc[a][b] = (f32x4){0.f, 0.f, 0.f, 0.f};
}

__device__ __forceinline__ void addB4(f32x4 acc[2][4], const float* bvec, int cg, int lane16) {
#pragma unroll
  for (int nti = 0; nti < 4; ++nti) {
    float bv = bvec[(cg * 4 + nti) * 16 + lane16];
#pragma unroll
    for (int rti = 0; rti < 2; ++rti)
#pragma unroll
      for (int r = 0; r < 4; ++r) acc[rti][nti][r] += bv;
  }
}

__device__ __forceinline__ void addE4(f32x4 acc[2][4], const float* __restrict__ E768,
                                      const int* __restrict__ tokS, int gateOff,
                                      int rtp, int cg, int lane16, int lg) {
#pragma unroll
  for (int rti = 0; rti < 2; ++rti)
#pragma unroll
    for (int r = 0; r < 4; ++r) {
      int grow = (rtp * 2 + rti) * 16 + lg * 4 + r;
      const float* er = E768 + tokS[grow] * 768 + gateOff;
#pragma unroll
      for (int nti = 0; nti < 4; ++nti)
        acc[rti][nti][r] += er[(cg * 4 + nti) * 16 + lane16];
    }
}

// LN over 256 cols/row in D-layout. red: [64 rows][4 cg][2].
__device__ __forceinline__ void lnD(f32x4 acc[2][4], int rtp, int cg, int lane16, int lg,
                                    float* red, const float* g, const float* b, bool relu) {
  float sv[2][4], qv[2][4];
#pragma unroll
  for (int rti = 0; rti < 2; ++rti)
#pragma unroll
    for (int r = 0; r < 4; ++r) {
      float s = 0.f, q = 0.f;
#pragma unroll
      for (int nti = 0; nti < 4; ++nti) { float v = acc[rti][nti][r]; s += v; q += v * v; }
#pragma unroll
      for (int m = 1; m < 16; m <<= 1) { s += __shfl_xor(s, m); q += __shfl_xor(q, m); }
      sv[rti][r] = s; qv[rti][r] = q;
    }
  __syncthreads();
  if (lane16 == 0) {
#pragma unroll
    for (int rti = 0; rti < 2; ++rti)
#pragma unroll
      for (int r = 0; r < 4; ++r) {
        int grow = (rtp * 2 + rti) * 16 + lg * 4 + r;
        red[grow * 8 + cg * 2] = sv[rti][r];
        red[grow * 8 + cg * 2 + 1] = qv[rti][r];
      }
  }
  __syncthreads();
  float gv[4], bv[4];
#pragma unroll
  for (int nti = 0; nti < 4; ++nti) {
    int gc = (cg * 4 + nti) * 16 + lane16;
    gv[nti] = g[gc]; bv[nti] = b[gc];
  }
#pragma unroll
  for (int rti = 0; rti < 2; ++rti)
#pragma unroll
    for (int r = 0; r < 4; ++r) {
      int grow = (rtp * 2 + rti) * 16 + lg * 4 + r;
      float s = red[grow * 8 + 0] + red[grow * 8 + 2] + red[grow * 8 + 4] + red[grow * 8 + 6];
      float q = red[grow * 8 + 1] + red[grow * 8 + 3] + red[grow * 8 + 5] + red[grow * 8 + 7];
      float mean = s * (1.f / 256.f);
      float var = q * (1.f / 256.f) - mean * mean;
      float rstd = rsqrtf(var + 1e-5f);
#pragma unroll
      for (int nti = 0; nti < 4; ++nti) {
        float v = (acc[rti][nti][r] - mean) * rstd * gv[nti] + bv[nti];
        acc[rti][nti][r] = relu ? fmaxf(v, 0.f) : v;
      }
    }
}

__device__ __forceinline__ void scatD(f16* X, const f32x4 acc[2][4], int rtp, int cg,
                                      int lane16, int lg) {
#pragma unroll
  for (int rti = 0; rti < 2; ++rti)
#pragma unroll
    for (int r = 0; r < 4; ++r) {
      int grow = (rtp * 2 + rti) * 16 + lg * 4 + r;
#pragma unroll
      for (int nti = 0; nti < 4; ++nti) {
        int gc = (cg * 4 + nti) * 16 + lane16;
        X[(size_t)grow * AST2 + gc] = (f16)acc[rti][nti][r];
      }
    }
}

__device__ __forceinline__ void stageH(f16* dst, const float* __restrict__ src,
                                       int nv, int t) {
#pragma unroll
  for (int ii = 0; ii < 4; ++ii) {
    int i = t + ii * TPM;               // 2048 chunks of 8
    int r = i >> 5, c8 = i & 31;
    f16x8 h = (f16x8)(_Float16)0;
    if (r < nv) {
      const float* p = src + (size_t)r * HD + c8 * 8;
      float4 v0 = *(const float4*)p, v1 = *(const float4*)(p + 4);
      h[0] = (f16)v0.x; h[1] = (f16)v0.y; h[2] = (f16)v0.z; h[3] = (f16)v0.w;
      h[4] = (f16)v1.x; h[5] = (f16)v1.y; h[6] = (f16)v1.z; h[7] = (f16)v1.w;
    }
    *(f16x8*)(dst + (size_t)r * AST2 + c8 * 8) = h;
  }
}

// ---------------- the f16-MFMA fused kernel (f32 world) ----------------
__global__ __launch_bounds__(TPM, 4) void k_mfma(
    const int* __restrict__ flag, int Brows,
    const float* __restrict__ node_i, const float* __restrict__ node_j,
    const float* __restrict__ latent, const float* __restrict__ hin,
    const int* __restrict__ tok,
    const float* __restrict__ be, const float* __restrict__ ge, const float* __restrict__ bee,
    const float* __restrict__ gn, const float* __restrict__ bn,
    const float* __restrict__ b_hh,
    const float* __restrict__ bfb, const float* __restrict__ gf, const float* __restrict__ bff,
    const float* __restrict__ b1, const float* __restrict__ W2, const float* __restrict__ b2,
    const f16* __restrict__ WeF, const f16* __restrict__ WihF,
    const f16* __restrict__ WhhF, const f16* __restrict__ WfF,
    const f16* __restrict__ W1F,
    const float* __restrict__ Wcvo, const float* __restrict__ bcvo,
    const float* __restrict__ E768,
    float* __restrict__ outL, float* __restrict__ outNH) {
  if (*flag != 0) return;
  extern __shared__ char smc[];
  f16* X1 = (f16*)smc;                         // [64][AST2] 33792 B
  f16* X2 = (f16*)(smc + 33792);               // [64][AST2] 33792 B
  float* red = (float*)(smc + 67584);          // 1024 f32
  float* sc  = (float*)(smc + 71680);          // 512 f32 (latent)
  int* tokS  = (int*)(smc + 73728);            // 64 ints

  const int t = threadIdx.x;
  const int w = __builtin_amdgcn_readfirstlane(t >> 6);  // 0..7
  const int l = t & 63;
  const int lane16 = l & 15, lg = l >> 4;
  const int rtp = w & 1;                // rows rtp*32..+32
  const int cg = w >> 1;                // col-tiles cg*4..+4
  const int rowBase = rtp * 32;
  const int row0 = blockIdx.x * RPB;
  int nv = Brows - row0; if (nv > RPB) nv = RPB;

  if (t < 64) tokS[t] = (t < nv) ? tok[row0 + t] : 0;
  if (t < 512) sc[t] = ((t >> 3) < nv) ? latent[(size_t)row0 * 8 + t] : 0.f;
  stageH(X1, node_i + (size_t)row0 * HD, nv, t);
  __syncthreads();                                                  // B1

  // ---- EDGE = relu(LN([ni|nj]@We + be)) ----
  f32x4 acc[2][4];
  zero4(acc);
  mm4(acc, X1, rowBase, 0, 8, WeF, 16, 0, cg * 4, lane16, lg, l);
  __syncthreads();                                                  // B2
  stageH(X1, node_j + (size_t)row0 * HD, nv, t);
  __syncthreads();                                                  // B3
  mm4(acc, X1, rowBase, 0, 8, WeF, 16, 8, cg * 4, lane16, lg, l);
  addB4(acc, be, cg, lane16);
  lnD(acc, rtp, cg, lane16, lg, red, ge, bee, true);                // B4,B5
  scatD(X2, acc, rtp, cg, lane16, lg);                              // X2 = edge
  __syncthreads();                                                  // B6

  // ---- fusion acc: edge part ----
  f32x4 fac[2][4];
  zero4(fac);
  mm4(fac, X2, rowBase, 0, 8, WfF, 16, 0, cg * 4, lane16, lg, l);

  // ---- attended = LN(latent@Wcvo + bcvo) (VALU, K=8) ----
  {
    float a32[32];
#pragma unroll
    for (int j4 = 0; j4 < 8; ++j4) {
      float4 v = *(const float4*)(bcvo + w * 32 + j4 * 4);
      a32[j4 * 4 + 0] = v.x; a32[j4 * 4 + 1] = v.y;
      a32[j4 * 4 + 2] = v.z; a32[j4 * 4 + 3] = v.w;
    }
#pragma unroll
    for (int k = 0; k < 8; ++k) {
      float xs = sc[l * 8 + k];
      const float* wr = Wcvo + k * 256 + w * 32;
#pragma unroll
      for (int j4 = 0; j4 < 8; ++j4) {
        float4 wv = *(const float4*)(wr + j4 * 4);
        a32[j4 * 4 + 0] = fmaf(xs, wv.x, a32[j4 * 4 + 0]);
        a32[j4 * 4 + 1] = fmaf(xs, wv.y, a32[j4 * 4 + 1]);
        a32[j4 * 4 + 2] = fmaf(xs, wv.z, a32[j4 * 4 + 2]);
        a32[j4 * 4 + 3] = fmaf(xs, wv.w, a32[j4 * 4 + 3]);
      }
    }
    float s = 0.f, q = 0.f;
#pragma unroll
    for (int j = 0; j < 32; ++j) { s += a32[j]; q += a32[j] * a32[j]; }
    __syncthreads();                                                // B7
    red[(w * 64 + l) * 2] = s; red[(w * 64 + l) * 2 + 1] = q;
    __syncthreads();                                                // B8
    s = 0.f; q = 0.f;
#pragma unroll
    for (int ww = 0; ww < 8; ++ww) {
      s += red[(ww * 64 + l) * 2]; q += red[(ww * 64 + l) * 2 + 1];
    }
    float mean = s * (1.f / 256.f);
    float var = q * (1.f / 256.f) - mean * mean;
    float rstd = rsqrtf(var + 1e-5f);
#pragma unroll
    for (int j = 0; j < 32; j += 2) {
      float v0 = (a32[j] - mean) * rstd * gn[w * 32 + j] + bn[w * 32 + j];
      float v1 = (a32[j + 1] - mean) * rstd * gn[w * 32 + j + 1] + bn[w * 32 + j + 1];
      union { f16 h[2]; unsigned u; } pu;
      pu.h[0] = (f16)v0; pu.h[1] = (f16)v1;
      *(unsigned*)(X1 + (size_t)l * AST2 + w * 32 + j) = pu.u;
    }
  }
  __syncthreads();                                                  // B9: X1 = attended

  // ---- fusion: att part; stage hin ----
  mm4(fac, X1, rowBase, 0, 8, WfF, 16, 8, cg * 4, lane16, lg, l);
  stageH(X2, hin + (size_t)row0 * HD, nv, t);
  __syncthreads();                                                  // B10: X2 = hin(f16)

  // ---- GRU ----
  f32x4 ghn[2][4];
  zero4(ghn);
  mm4(ghn, X2, rowBase, 0, 8, WhhF, 48, 0, 32 + cg * 4, lane16, lg, l);
  addB4(ghn, b_hh + 512, cg, lane16);

  zero4(acc);  // acc_r
  mm4(acc, X1, rowBase, 0, 8, WihF, 48, 0, cg * 4, lane16, lg, l);
  mm4(acc, X2, rowBase, 0, 8, WhhF, 48, 0, cg * 4, lane16, lg, l);
  addE4(acc, E768, tokS, 0, rtp, cg, lane16, lg);
  addB4(acc, b_hh, cg, lane16);
#pragma unroll
  for (int a = 0; a < 2; ++a)
#pragma unroll
    for (int b = 0; b < 4; ++b)
#pragma unroll
      for (int r = 0; r < 4; ++r) {
        float rr = 1.f / (1.f + expf(-acc[a][b][r]));
        acc[a][b][r] = rr * ghn[a][b][r];       // acc = r * ghn
      }

  zero4(ghn);  // reuse as gi_n
  mm4(ghn, X1, rowBase, 0, 8, WihF, 48, 0, 32 + cg * 4, lane16, lg, l);
  addE4(ghn, E768, tokS, 512, rtp, cg, lane16, lg);
#pragma unroll
  for (int a = 0; a < 2; ++a)
#pragma unroll
    for (int b = 0; b < 4; ++b)
#pragma unroll
      for (int r = 0; r < 4; ++r)
        ghn[a][b][r] = tanhf(ghn[a][b][r] + acc[a][b][r]);  // ghn = n

  zero4(acc);  // acc_z
  mm4(acc, X1, rowBase, 0, 8, WihF, 48, 0, 16 + cg * 4, lane16, lg, l);
  mm4(acc, X2, rowBase, 0, 8, WhhF, 48, 0, 16 + cg * 4, lane16, lg, l);
  addE4(acc, E768, tokS, 256, rtp, cg, lane16, lg);
  addB4(acc, b_hh + 256, cg, lane16);
#pragma unroll
  for (int a = 0; a < 2; ++a)
#pragma unroll
    for (int r = 0; r < 4; ++r) {
      int grow = (rtp * 2 + a) * 16 + lg * 4 + r;
      const float* hrow = hin + (size_t)(row0 + grow) * HD;
      bool live = grow < nv;
#pragma unroll
      for (int b = 0; b < 4; ++b) {
        int gc = (cg * 4 + b) * 16 + lane16;
        float zz = 1.f / (1.f + expf(-acc[a][b][r]));
        float hvv = live ? hrow[gc] : 0.f;      // exact f32 h
        float nh = (1.f - zz) * ghn[a][b][r] + zz * hvv;
        acc[a][b][r] = nh;
        if (live) outNH[(size_t)(row0 + grow) * HD + gc] = nh;  // exact f32 out
      }
    }
  __syncthreads();                                                  // B11
  scatD(X1, acc, rtp, cg, lane16, lg);                              // X1 = newh(f16)
  __syncthreads();                                                  // B12

  // ---- fusion: newh part; fused = relu(LN(fac + bfb)) ----
  mm4(fac, X1, rowBase, 0, 8, WfF, 16, 16, cg * 4, lane16, lg, l);
  addB4(fac, bfb, cg, lane16);
  lnD(fac, rtp, cg, lane16, lg, red, gf, bff, true);                // B13,B14
  scatD(X2, fac, rtp, cg, lane16, lg);                              // X2 = fused
  __syncthreads();                                                  // B15

  // ---- head: h1 = relu(fused@W1 + b1) ----
  f32x4 acc1[2][2];
#pragma unroll
  for (int a = 0; a < 2; ++a)
#pragma unroll
    for (int b = 0; b < 2; ++b) acc1[a][b] = (f32x4){0.f, 0.f, 0.f, 0.f};
  mm2(acc1, X2, rowBase, W1F, cg * 2, lane16, lg, l);
  float* H = (float*)X1;               // [64][132] f32 (X1 dead after B13)
#pragma unroll
  for (int a = 0; a < 2; ++a)
#pragma unroll
    for (int r = 0; r < 4; ++r) {
      int grow = (rtp * 2 + a) * 16 + lg * 4 + r;
#pragma unroll
      for (int b = 0; b < 2; ++b) {
        int gc1 = (cg * 2 + b) * 16 + lane16;
        H[grow * 132 + gc1] = fmaxf(acc1[a][b][r] + b1[gc1], 0.f);
      }
    }
  __syncthreads();                                                  // B16

  // ---- logits = h1@W2 + b2 (split-K over 8 waves) ----
  {
    int rr = t & 63, ks = w * 16;
    float p[8];
#pragma unroll
    for (int o = 0; o < 8; ++o) p[o] = 0.f;
    for (int k = 0; k < 16; ++k) {
      float hv = H[rr * 132 + ks + k];
      const float* w2r = W2 + (size_t)(ks + k) * 8;
#pragma unroll
      for (int o = 0; o < 8; ++o) p[o] = fmaf(hv, w2r[o], p[o]);
    }
    float* hp = (float*)X2;            // [8][64][8] f32 (fused consumed)
#pragma unroll
    for (int o = 0; o < 8; ++o) hp[(w * 64 + rr) * 8 + o] = p[o];
  }
  __syncthreads();                                                  // B17
  if (t < 64 && t < nv) {
    const float* hp = (const float*)X2;
    float o8[8];
#pragma unroll
    for (int o = 0; o < 8; ++o) {
      float s = b2[o];
#pragma unroll
      for (int ww = 0; ww < 8; ++ww) s += hp[(ww * 64 + t) * 8 + o];
      o8[o] = s;
    }
    *(float4*)(outL + (size_t)(row0 + t) * 8) = make_float4(o8[0], o8[1], o8[2], o8[3]);
    *(float4*)(outL + (size_t)(row0 + t) * 8 + 4) = make_float4(o8[4], o8[5], o8[6], o8[7]);
  }
}

// ================= VALU fallback path (R5 structure, verified) =================
template <int K, int LDW, class XT, class WT>
__device__ __forceinline__ void gemm16(float* __restrict__ acc, const XT* __restrict__ x,
                                       const WT* __restrict__ wb) {
#pragma unroll 2
  for (int k = 0; k < K; k += 4) {
    float4 xv = ld4c(x + k);
#pragma unroll
    for (int kk = 0; kk < 4; ++kk) {
      float xs = (kk == 0) ? xv.x : (kk == 1) ? xv.y : (kk == 2) ? xv.z : xv.w;
      const WT* wr = wb + (size_t)(k + kk) * LDW;
#pragma unroll
      for (int j = 0; j < 4; ++j) {
        float4 wv = ld4c(wr + j * 4);
        acc[j*4+0] = fmaf(xs, wv.x, acc[j*4+0]);
        acc[j*4+1] = fmaf(xs, wv.y, acc[j*4+1]);
        acc[j*4+2] = fmaf(xs, wv.z, acc[j*4+2]);
        acc[j*4+3] = fmaf(xs, wv.w, acc[j*4+3]);
      }
    }
  }
}

template <int K, int LDW, class XT, class WT>
__device__ __forceinline__ void gemm8(float* __restrict__ acc, const XT* __restrict__ x,
                                      const WT* __restrict__ wb) {
#pragma unroll 2
  for (int k = 0; k < K; k += 4) {
    float4 xv = ld4c(x + k);
#pragma unroll
    for (int kk = 0; kk < 4; ++kk) {
      float xs = (kk == 0) ? xv.x : (kk == 1) ? xv.y : (kk == 2) ? xv.z : xv.w;
      const WT* wr = wb + (size_t)(k + kk) * LDW;
#pragma unroll
      for (int j = 0; j < 2; ++j) {
        float4 wv = ld4c(wr + j * 4);
        acc[j*4+0] = fmaf(xs, wv.x, acc[j*4+0]);
        acc[j*4+1] = fmaf(xs, wv.y, acc[j*4+1]);
        acc[j*4+2] = fmaf(xs, wv.z, acc[j*4+2]);
        acc[j*4+3] = fmaf(xs, wv.w, acc[j*4+3]);
      }
    }
  }
}

template <class WT>
__device__ __forceinline__ void ld16v(float* d, const WT* p) {
#pragma unroll
  for (int j = 0; j < 4; ++j) {
    float4 v = ld4c(p + j * 4);
    d[j*4+0] = v.x; d[j*4+1] = v.y; d[j*4+2] = v.z; d[j*4+3] = v.w;
  }
}
template <class WT>
__device__ __forceinline__ void add16v(float* d, const WT* p) {
#pragma unroll
  for (int j = 0; j < 4; ++j) {
    float4 v = ld4c(p + j * 4);
    d[j*4+0] += v.x; d[j*4+1] += v.y; d[j*4+2] += v.z; d[j*4+3] += v.w;
  }
}
__device__ __forceinline__ void st16v(float* p, const float* a) {
#pragma unroll
  for (int j = 0; j < 4; ++j)
    *(float4*)(p + j * 4) = make_float4(a[j*4+0], a[j*4+1], a[j*4+2], a[j*4+3]);
}

template <bool RELU, class WT>
__device__ __forceinline__ void ln_apply16(float* acc, float mean, float rstd,
                                           const WT* g, const WT* b) {
#pragma unroll
  for (int j = 0; j < 4; ++j) {
    float4 gv = ld4c(g + j * 4), bv = ld4c(b + j * 4);
    acc[j*4+0] = (acc[j*4+0] - mean) * rstd * gv.x + bv.x;
    acc[j*4+1] = (acc[j*4+1] - mean) * rstd * gv.y + bv.y;
    acc[j*4+2] = (acc[j*4+2] - mean) * rstd * gv.z + bv.z;
    acc[j*4+3] = (acc[j*4+3] - mean) * rstd * gv.w + bv.w;
    if (RELU) {
      acc[j*4+0] = fmaxf(acc[j*4+0], 0.f);
      acc[j*4+1] = fmaxf(acc[j*4+1], 0.f);
      acc[j*4+2] = fmaxf(acc[j*4+2], 0.f);
      acc[j*4+3] = fmaxf(acc[j*4+3], 0.f);
    }
  }
}

__device__ __forceinline__ void ln_stats16(const float* acc, int w, int l, float* red,
                                           float& mean, float& rstd) {
  float s = 0.f, q = 0.f;
#pragma unroll
  for (int j = 0; j < 16; ++j) { s += acc[j]; q += acc[j] * acc[j]; }
  __syncthreads();
  *(float2*)(red + (w * 64 + l) * 2) = make_float2(s, q);
  __syncthreads();
  s = 0.f; q = 0.f;
#pragma unroll
  for (int ww = 0; ww < 16; ++ww) {
    float2 v = *(const float2*)(red + (ww * 64 + l) * 2);
    s += v.x; q += v.y;
  }
  mean = s * (1.f / 256.f);
  float var = q * (1.f / 256.f) - mean * mean;
  rstd = rsqrtf(var + 1e-5f);
}

template <class T>
__device__ __forceinline__ void stage256(float* dst, const T* __restrict__ src, int nv, int t) {
#pragma unroll
  for (int ii = 0; ii < 4; ++ii) {
    int i = t + ii * TPB;
    int r = i >> 6, c4 = i & 63;
    float4 v = make_float4(0.f, 0.f, 0.f, 0.f);
    if (r < nv) v = ld4c(src + (size_t)r * HD + c4 * 4);
    *(float4*)(dst + r * AST + c4 * 4) = v;
  }
}

template <class T, class WT, int WANT>
__global__ __launch_bounds__(TPB, 4) void k_row(
    const int* __restrict__ flag, int Brows,
    const T* __restrict__ node_i, const T* __restrict__ node_j,
    const T* __restrict__ latent, const T* __restrict__ hin,
    const int* __restrict__ tok,
    const WT* __restrict__ We, const WT* __restrict__ be,
    const WT* __restrict__ ge, const WT* __restrict__ bee,
    const WT* __restrict__ gn, const WT* __restrict__ bn,
    const WT* __restrict__ emb,
    const WT* __restrict__ W_ih, const WT* __restrict__ b_ih,
    const WT* __restrict__ W_hh, const WT* __restrict__ b_hh,
    const WT* __restrict__ Wf, const WT* __restrict__ bfb,
    const WT* __restrict__ gf, const WT* __restrict__ bff,
    const WT* __restrict__ W1, const WT* __restrict__ b1,
    const WT* __restrict__ W2, const WT* __restrict__ b2,
    const float* __restrict__ Wcvo, const float* __restrict__ bcvo,
    T* __restrict__ outL, T* __restrict__ outNH) {
  if (*flag != WANT) return;
  extern __shared__ float sm[];
  float* A   = sm;
  float* Bb  = sm + 64 * AST;
  float* red = sm + 2 * 64 * AST;
  float* sc  = red + 2048;
  int* tokS  = (int*)(sc + 512);

  const int t = threadIdx.x;
  const int w = __builtin_amdgcn_readfirstlane(t >> 6);
  const int l = t & 63;
  const int row0 = blockIdx.x * RPB;
  int nv = Brows - row0; if (nv > RPB) nv = RPB;
  const int cb = w * 16;

  if (t < 64) tokS[t] = (t < nv) ? tok[row0 + t] : 0;
  stage256(A, node_i + (size_t)row0 * HD, nv, t);
  __syncthreads();

  float acc[16];
  ld16v(acc, be + cb);
  gemm16<256, 256>(acc, A + l * AST, We + cb);
  __syncthreads();
  stage256(A, node_j + (size_t)row0 * HD, nv, t);
  __syncthreads();
  gemm16<256, 256>(acc, A + l * AST, We + (size_t)256 * 256 + cb);
  float mean, rstd;
  ln_stats16(acc, w, l, red, mean, rstd);
  ln_apply16<true>(acc, mean, rstd, ge + cb, bee + cb);
  st16v(Bb + l * AST + cb, acc);
  __syncthreads();

  float fac[16];
  ld16v(fac, bfb + cb);
  gemm16<256, 256>(fac, Bb + l * AST, Wf + cb);

  if (t < 512) {
    int r = t >> 3;
    sc[t] = (r < nv) ? ld(latent + (size_t)row0 * 8 + t) : 0.f;
  }
  __syncthreads();
  ld16v(acc, bcvo + cb);
  gemm16<8, 256>(acc, sc + l * 8, Wcvo + cb);
  ln_stats16(acc, w, l, red, mean, rstd);
  ln_apply16<false>(acc, mean, rstd, gn + cb, bn + cb);
  st16v(A + l * AST + cb, acc);
  __syncthreads();

  gemm16<256, 256>(fac, A + l * AST, Wf + (size_t)256 * 256 + cb);
  stage256(Bb, hin + (size_t)row0 * HD, nv, t);
  __syncthreads();

  const int tk = tokS[l];
  const WT* embr = emb + (size_t)tk * HD;

  ld16v(acc, b_ih + cb); add16v(acc, b_hh + cb);
  gemm16<256, 768>(acc, A + l * AST, W_ih + cb);
  gemm16<256, 768>(acc, embr, W_ih + (size_t)256 * 768 + cb);
  gemm16<256, 768>(acc, Bb + l * AST, W_hh + cb);
  float rg[16];
#pragma unroll
  for (int j = 0; j < 16; ++j) rg[j] = 1.f / (1.f + expf(-acc[j]));

  ld16v(acc, b_hh + 512 + cb);
  gemm16<256, 768>(acc, Bb + l * AST, W_hh + 512 + cb);
#pragma unroll
  for (int j = 0; j < 16; ++j) rg[j] *= acc[j];

  ld16v(acc, b_ih + 512 + cb);
  gemm16<256, 768>(acc, A + l * AST, W_ih + 512 + cb);
  gemm16<256, 768>(acc, embr, W_ih + (size_t)256 * 768 + 512 + cb);
#pragma unroll
  for (int j = 0; j < 16; ++j) rg[j] = tanhf(acc[j] + rg[j]);

  ld16v(acc, b_ih + 256 + cb); add16v(acc, b_hh + 256 + cb);
  gemm16<256, 768>(acc, A + l * AST, W_ih + 256 + cb);
  gemm16<256, 768>(acc, embr, W_ih + (size_t)256 * 768 + 256 + cb);
  gemm16<256, 768>(acc, Bb + l * AST, W_hh + 256 + cb);
  __syncthreads();
#pragma unroll
  for (int j4 = 0; j4 < 4; ++j4) {
    float4 hv = ld4c(Bb + l * AST + cb + j4 * 4);
    float z0 = 1.f / (1.f + expf(-acc[j4*4+0]));
    float z1 = 1.f / (1.f + expf(-acc[j4*4+1]));
    float z2 = 1.f / (1.f + expf(-acc[j4*4+2]));
    float z3 = 1.f / (1.f + expf(-acc[j4*4+3]));
    acc[j4*4+0] = (1.f - z0) * rg[j4*4+0] + z0 * hv.x;
    acc[j4*4+1] = (1.f - z1) * rg[j4*4+1] + z1 * hv.y;
    acc[j4*4+2] = (1.f - z2) * rg[j4*4+2] + z2 * hv.z;
    acc[j4*4+3] = (1.f - z3) * rg[j4*4+3] + z3 * hv.w;
  }
  st16v(Bb + l * AST + cb, acc);
  __syncthreads();

  for (int i = t; i < nv * HD; i += TPB) {
    int r = i >> 8, c = i & 255;
    outNH[(size_t)(row0 + r) * HD + c] = (T)Bb[r * AST + c];
  }

  gemm16<256, 256>(fac, Bb + l * AST, Wf + (size_t)512 * 256 + cb);
  ln_stats16(fac, w, l, red, mean, rstd);
  ln_apply16<true>(fac, mean, rstd, gf + cb, bff + cb);
  st16v(A + l * AST + cb, fac);
  __syncthreads();

  float h1[8];
  {
    float4 v0 = ld4c(b1 + w * 8), v1 = ld4c(b1 + w * 8 + 4);
    h1[0]=v0.x; h1[1]=v0.y; h1[2]=v0.z; h1[3]=v0.w;
    h1[4]=v1.x; h1[5]=v1.y; h1[6]=v1.z; h1[7]=v1.w;
  }
  gemm8<256, 128>(h1, A + l * AST, W1 + w * 8);
  float part[8];
#pragma unroll
  for (int o = 0; o < 8; ++o) part[o] = 0.f;
#pragma unroll
  for (int kk = 0; kk < 8; ++kk) {
    float hval = fmaxf(h1[kk], 0.f);
    const WT* w2r = W2 + (size_t)(w * 8 + kk) * 8;
    float4 a0 = ld4c(w2r), a1 = ld4c(w2r + 4);
    part[0] = fmaf(hval, a0.x, part[0]);
    part[1] = fmaf(hval, a0.y, part[1]);
    part[2] = fmaf(hval, a0.z, part[2]);
    part[3] = fmaf(hval, a0.w, part[3]);
    part[4] = fmaf(hval, a1.x, part[4]);
    part[5] = fmaf(hval, a1.y, part[5]);
    part[6] = fmaf(hval, a1.z, part[6]);
    part[7] = fmaf(hval, a1.w, part[7]);
  }
  float* hp = Bb;
  *(float4*)(hp + (w * 64 + l) * 8)     = make_float4(part[0], part[1], part[2], part[3]);
  *(float4*)(hp + (w * 64 + l) * 8 + 4) = make_float4(part[4], part[5], part[6], part[7]);
  __syncthreads();
  if (w == 0 && l < nv) {
#pragma unroll
    for (int o = 0; o < 8; ++o) {
      float lg = ld(b2 + o);
#pragma unroll
      for (int ww = 0; ww < 16; ++ww) lg += hp[(ww * 64 + l) * 8 + o];
      outL[(size_t)(row0 + l) * 8 + o] = (T)lg;
    }
  }
}

// ---------------- launch ----------------
extern "C" void kernel_launch(void* const* d_in, const int* in_sizes, int n_in,
                              void* d_out, int out_size, void* d_ws, size_t ws_size,
                              hipStream_t stream) {
  char* ws = (char*)d_ws;
  const int B = in_sizes[0] / HD;
  const int nblk = (B + RPB - 1) / RPB;
  int* flag = (int*)ws;
  float* tmpcv = (float*)(ws + 1024);
  float* Wcvo  = (float*)(ws + 16384);
  float* bcvo  = (float*)(ws + 24576);
  float* E768  = (float*)(ws + 28672);
  f16*   fragW = (f16*)(ws + FB_OFF);

  int nw = B * 128; if (nw > 16384) nw = 16384;
  k_detect<<<1, 256, 0, stream>>>((const unsigned int*)d_in[0], flag, nw);

  const size_t SMEM_F = (size_t)(2 * 64 * AST + 2048 + 512) * 4 + 64 * 4;
  const size_t SMEM_M = 73984;

  // ---- f32 world: f16 MFMA (fallback: VALU k_row) ----
  {
    auto P = [&](int i) { return (const float*)d_in[i]; };
    k_cvo_a<float, 0><<<9, 256, 0, stream>>>(flag, P(9), P(15), P(10), P(16), tmpcv);
    k_cvo_b<float, 0><<<9, 256, 0, stream>>>(flag, tmpcv, P(17), P(18), Wcvo, bcvo);
    if (ws_size >= (size_t)WS_NEED) {
      k_prep<<<512, 256, 0, stream>>>(flag, P(5), P(22), P(24), P(26), P(30), fragW);
      k_egru<<<8, 768, 0, stream>>>(flag, P(21), P(22), P(23), E768);
      (void)hipFuncSetAttribute(reinterpret_cast<const void*>(&k_mfma),
                                hipFuncAttributeMaxDynamicSharedMemorySize, (int)SMEM_M);
      k_mfma<<<nblk, TPM, SMEM_M, stream>>>(
          flag, B, P(0), P(1), P(2), P(3), (const int*)d_in[4],
          P(6), P(7), P(8),                 // be, ge, bee
          P(19), P(20),                     // gn, bn
          P(25),                            // b_hh
          P(27), P(28), P(29),              // bfb, gf, bff
          P(31), P(32), P(33),              // b1, W2, b2
          fragW + WE_E, fragW + WIH_E, fragW + WHH_E, fragW + WF_E, fragW + W1_E,
          Wcvo, bcvo, E768,
          (float*)d_out, (float*)d_out + (size_t)B * 8);
    } else {
      (void)hipFuncSetAttribute(reinterpret_cast<const void*>(&k_row<float, float, 0>),
                                hipFuncAttributeMaxDynamicSharedMemorySize, (int)SMEM_F);
      k_row<float, float, 0><<<nblk, TPB, SMEM_F, stream>>>(
          flag, B, P(0), P(1), P(2), P(3), (const int*)d_in[4],
          P(5), P(6), P(7), P(8), P(19), P(20), P(21),
          P(22), P(23), P(24), P(25), P(26), P(27), P(28), P(29),
          P(30), P(31), P(32), P(33), Wcvo, bcvo,
          (float*)d_out, (float*)d_out + (size_t)B * 8);
    }
  }
  // ---- bf16 world (never observed live; safe fallback) ----
  {
    auto P = [&](int i) { return (const bf16*)d_in[i]; };
    k_cvo_a<bf16, 1><<<9, 256, 0, stream>>>(flag, P(9), P(15), P(10), P(16), tmpcv);
    k_cvo_b<bf16, 1><<<9, 256, 0, stream>>>(flag, tmpcv, P(17), P(18), Wcvo, bcvo);
    bf16* oL = (bf16*)d_out;
    (void)hipFuncSetAttribute(reinterpret_cast<const void*>(&k_row<bf16, bf16, 1>),
                              hipFuncAttributeMaxDynamicSharedMemorySize, (int)SMEM_F);
    k_row<bf16, bf16, 1><<<nblk, TPB, SMEM_F, stream>>>(
        flag, B, P(0), P(1), P(2), P(3), (const int*)d_in[4],
        P(5), P(6), P(7), P(8), P(19), P(20), P(21),
        P(22), P(23), P(24), P(25), P(26), P(27), P(28), P(29),
        P(30), P(31), P(32), P(33), Wcvo, bcvo, oL, oL + (size_t)B * 8);
  }
}

// Round 6
// 617.050 us; speedup vs baseline: 4.8759x; 1.0804x over previous
//
#include <hip/hip_runtime.h>

// LatentGuidedEdgeDecoder — round 9: kill GRU register spills + merge aux launches.
// R8 counters: k_mfma 453us, WRITE 429MB (vs 69 real), FETCH 330MB, VGPR=64,
// MfmaUtil 8.9%, VALUBusy 19%. Diagnosis: GRU phase holds fac+ghn+acc (96 f32)
// + ~32-48 transient frag regs > 128-VGPR cap (4 waves/EU) -> scratch spills;
// 512thr x 1024blk x ~170B round trips == the 360MB write excess. Kernel was
// memory-bound on its own spills.
// R9: (a) column-halved GRU (2 passes x 2 col-tiles, 16-f32 accumulators);
//     (b) newh never kept: blend with f16 h from LDS (err ~1e-3 << 0.0156
//         absmax) and store f32 straight to outNH; fusion re-reads outNH
//         (L2-hot, same-block rows) via f32->f16 converting A-frag loads;
//     (c) aux merged: detect, pre1(prep+egru+cvo_a dual-dtype), pre2(cvo_b),
//         k_mfma, bf16-fallback = 5 launches (was 9).

typedef __bf16 bf16;
typedef _Float16 f16;
typedef __attribute__((ext_vector_type(8))) _Float16 f16x8;
typedef __attribute__((ext_vector_type(4))) float f32x4;

#define HD 256
#define RPB 64
#define AST 260    // f32 fallback LDS stride (f32 elems)
#define AST2 264   // mfma LDS stride (f16 elems); row 528B
#define TPB 1024
#define TPM 512

// ws: flag@0 tmpcv@1024 Wcvo@16384 bcvo@24576 E768@28672(24576B) frag@65536
#define FB_OFF 65536
#define WE_E 0
#define WIH_E 131072
#define WHH_E 327680
#define WF_E 524288
#define W1_E 720896
#define FRAG_ELEMS 753664
#define WS_NEED (FB_OFF + FRAG_ELEMS * 2)

__device__ __forceinline__ float bf2f(unsigned short u) {
  union { unsigned int i; float f; } c; c.i = ((unsigned)u) << 16; return c.f;
}
__device__ __forceinline__ float4 ld4c(const float* p) { return *(const float4*)p; }
__device__ __forceinline__ float4 ld4c(const bf16* p) {
  ushort4 u = *(const ushort4*)p;
  return make_float4(bf2f(u.x), bf2f(u.y), bf2f(u.z), bf2f(u.w));
}
template <class T>
__device__ __forceinline__ float ld(const T* __restrict__ p) { return (float)*p; }

__device__ __forceinline__ f32x4 MFMA16(f16x8 a, f16x8 b, f32x4 c) {
  return __builtin_amdgcn_mfma_f32_16x16x32_f16(a, b, c, 0, 0, 0);
}

// ---------------- dtype detector ----------------
__global__ void k_detect(const unsigned int* __restrict__ wds, int* __restrict__ flag, int nw) {
  __shared__ int sRed[4];
  int t = threadIdx.x;
  int cnt = 0;
  for (int i = t; i < nw; i += 256) {
    unsigned e = (wds[i] >> 7) & 0xFFu;
    cnt += (e >= 110u && e <= 140u) ? 1 : 0;
  }
#pragma unroll
  for (int m = 1; m < 64; m <<= 1) cnt += __shfl_xor(cnt, m);
  if ((t & 63) == 0) sRed[t >> 6] = cnt;
  __syncthreads();
  if (t == 0) flag[0] = (sRed[0] + sRed[1] + sRed[2] + sRed[3] > nw / 2) ? 1 : 0;
}

// ---------------- pre1: weight reformat + E768 + cvo_a (dual dtype) ----------------
// blocks 0..511: prep (flag==0, doPrep); 512..519: egru (flag==0, doPrep); 520..528: cvo_a
__global__ void k_pre1(const int* __restrict__ flag, int doPrep,
                       const void* We, const void* Wih, const void* Whh,
                       const void* Wf, const void* W1,
                       const void* emb, const void* b_ih,
                       const void* Wc, const void* Wv, const void* bc, const void* bv,
                       f16* __restrict__ fragW, float* __restrict__ E768,
                       float* __restrict__ tmp) {
  const int fl = *flag;
  const int bid = blockIdx.x, t = threadIdx.x;
  if (bid < 512) {
    if (fl != 0 || !doPrep) return;
    const float* srcs[5] = {(const float*)We, (const float*)Wih, (const float*)Whh,
                            (const float*)Wf, (const float*)W1};
    const int Ns[5] = {256, 768, 768, 256, 128};
    const int offs[6] = {WE_E, WIH_E, WHH_E, WF_E, W1_E, FRAG_ELEMS};
    int g = bid * 256 + t, np = 512 * 256;
    for (int seg = 0; seg < 5; ++seg) {
      const float* s = srcs[seg];
      int N = Ns[seg], NT = N >> 4;
      f16* d = fragW + offs[seg];
      int n = offs[seg + 1] - offs[seg];
      for (int e = g; e < n; e += np) {
        int j = e & 7, lx = (e >> 3) & 63, tl = e >> 9;
        int kt = tl / NT, nt = tl - kt * NT;
        int sk = kt * 32 + ((lx >> 4) << 3) + j;
        int sn = nt * 16 + (lx & 15);
        d[e] = (f16)s[(size_t)sk * N + sn];
      }
    }
  } else if (bid < 520) {
    if (fl != 0 || !doPrep) return;
    int tok = bid - 512;
    const float* E = (const float*)emb;
    const float* W = (const float*)Wih;
    const float* B = (const float*)b_ih;
    for (int c = t; c < 768; c += 256) {
      float s = B[c];
      for (int k = 0; k < 256; ++k)
        s += E[tok * 256 + k] * W[(size_t)(256 + k) * 768 + c];
      E768[tok * 768 + c] = s;
    }
  } else {
    int i = bid - 520;  // 0..8
    int m = t;
    float s = 0.f;
    if (fl == 0) {
      const float* wc = (const float*)Wc; const float* wv = (const float*)Wv;
      const float* pc = (const float*)bc; const float* pv = (const float*)bv;
      if (i < 8) { for (int u = 0; u < 256; ++u) s += wc[i * 256 + u] * wv[(size_t)u * 256 + m]; }
      else { for (int u = 0; u < 256; ++u) s += pc[u] * wv[(size_t)u * 256 + m]; s += pv[m]; }
    } else {
      const bf16* wc = (const bf16*)Wc; const bf16* wv = (const bf16*)Wv;
      const bf16* pc = (const bf16*)bc; const bf16* pv = (const bf16*)bv;
      if (i < 8) { for (int u = 0; u < 256; ++u) s += ld(wc + i * 256 + u) * ld(wv + (size_t)u * 256 + m); }
      else { for (int u = 0; u < 256; ++u) s += ld(pc + u) * ld(wv + (size_t)u * 256 + m); s += ld(pv + m); }
    }
    tmp[i * 256 + m] = s;
  }
}

// ---------------- pre2: cvo_b (dual dtype) ----------------
__global__ void k_pre2(const int* __restrict__ flag, const float* __restrict__ tmp,
                       const void* Wo, const void* bo,
                       float* __restrict__ Wcvo, float* __restrict__ bcvo) {
  const int fl = *flag;
  int i = blockIdx.x, m = threadIdx.x;
  float s = 0.f;
  const float* tr = tmp + i * 256;
  if (fl == 0) {
    const float* wo = (const float*)Wo;
    for (int u = 0; u < 256; ++u) s += tr[u] * wo[(size_t)u * 256 + m];
    if (i < 8) Wcvo[i * 256 + m] = s;
    else       bcvo[m] = s + ((const float*)bo)[m];
  } else {
    const bf16* wo = (const bf16*)Wo;
    for (int u = 0; u < 256; ++u) s += tr[u] * ld(wo + (size_t)u * 256 + m);
    if (i < 8) Wcvo[i * 256 + m] = s;
    else       bcvo[m] = s + ld((const bf16*)bo + m);
  }
}

// ---------------- MFMA micro-helpers ----------------
// 4 col-tiles, A from LDS f16
__device__ __forceinline__ void mm4(f32x4 acc[2][4], const f16* __restrict__ X,
                                    int rowBase, const f16* __restrict__ WB, int NT,
                                    int ktB0, int ntB, int lane16, int lg, int l) {
#pragma unroll 2
  for (int kt = 0; kt < 8; ++kt) {
    const f16* xp = X + (size_t)(rowBase + lane16) * AST2 + kt * 32 + lg * 8;
    f16x8 a0 = *(const f16x8*)xp;
    f16x8 a1 = *(const f16x8*)(xp + 16 * AST2);
    const f16* wp = WB + (((size_t)(ktB0 + kt) * NT + ntB) * 64 + l) * 8;
#pragma unroll
    for (int nti = 0; nti < 4; ++nti) {
      f16x8 bfr = *(const f16x8*)(wp + nti * 512);
      acc[0][nti] = MFMA16(a0, bfr, acc[0][nti]);
      acc[1][nti] = MFMA16(a1, bfr, acc[1][nti]);
    }
  }
}

// 2 col-tiles, A from LDS f16 (GRU halves, W1 head)
__device__ __forceinline__ void mmh(f32x4 acc[2][2], const f16* __restrict__ X,
                                    int rowBase, const f16* __restrict__ WB, int NT,
                                    int ntB, int lane16, int lg, int l) {
#pragma unroll 2
  for (int kt = 0; kt < 8; ++kt) {
    const f16* xp = X + (size_t)(rowBase + lane16) * AST2 + kt * 32 + lg * 8;
    f16x8 a0 = *(const f16x8*)xp;
    f16x8 a1 = *(const f16x8*)(xp + 16 * AST2);
    const f16* wp = WB + (((size_t)kt * NT + ntB) * 64 + l) * 8;
#pragma unroll
    for (int nti = 0; nti < 2; ++nti) {
      f16x8 bfr = *(const f16x8*)(wp + nti * 512);
      acc[0][nti] = MFMA16(a0, bfr, acc[0][nti]);
      acc[1][nti] = MFMA16(a1, bfr, acc[1][nti]);
    }
  }
}

// 4 col-tiles, A from GLOBAL f32 (outNH re-read), cvt to f16 in-flight
__device__ __forceinline__ void mm4g(f32x4 acc[2][4], const float* __restrict__ Xg,
                                     int rowBase, const f16* __restrict__ WB, int NT,
                                     int ktB0, int ntB, int lane16, int lg, int l) {
#pragma unroll 2
  for (int kt = 0; kt < 8; ++kt) {
    const float* xp = Xg + (size_t)(rowBase + lane16) * HD + kt * 32 + lg * 8;
    float4 u0 = *(const float4*)xp, u1 = *(const float4*)(xp + 4);
    f16x8 a0;
    a0[0] = (f16)u0.x; a0[1] = (f16)u0.y; a0[2] = (f16)u0.z; a0[3] = (f16)u0.w;
    a0[4] = (f16)u1.x; a0[5] = (f16)u1.y; a0[6] = (f16)u1.z; a0[7] = (f16)u1.w;
    const float* yp = xp + 16 * HD;
    float4 v0 = *(const float4*)yp, v1 = *(const float4*)(yp + 4);
    f16x8 a1;
    a1[0] = (f16)v0.x; a1[1] = (f16)v0.y; a1[2] = (f16)v0.z; a1[3] = (f16)v0.w;
    a1[4] = (f16)v1.x; a1[5] = (f16)v1.y; a1[6] = (f16)v1.z; a1[7] = (f16)v1.w;
    const f16* wp = WB + (((size_t)(ktB0 + kt) * NT + ntB) * 64 + l) * 8;
#pragma unroll
    for (int nti = 0; nti < 4; ++nti) {
      f16x8 bfr = *(const f16x8*)(wp + nti * 512);
      acc[0][nti] = MFMA16(a0, bfr, acc[0][nti]);
      acc[1][nti] = MFMA16(a1, bfr, acc[1][nti]);
    }
  }
}

__device__ __forceinline__ void zero4(f32x4 acc[2][4]) {
#pragma unroll
  for (int a = 0; a < 2; ++a)
#pragma unroll
    for (int b = 0; b < 4; ++b) acc[a][b] = (f32x4){0.f, 0.f, 0.f, 0.f};
}
__device__ __forceinline__ void zero2(f32x4 acc[2][2]) {
#pragma unroll
  for (int a = 0; a < 2; ++a)
#pragma unroll
    for (int b = 0; b < 2; ++b) acc[a][b] = (f32x4){0.f, 0.f, 0.f, 0.f};
}

__device__ __forceinline__ void addB4(f32x4 acc[2][4], const float* bvec, int cg, int lane16) {
#pragma unroll
  for (int nti = 0; nti < 4; ++nti) {
    float bv = bvec[(cg * 4 + nti) * 16 + lane16];
#pragma unroll
    for (int rti = 0; rti < 2; ++rti)
#pragma unroll
      for (int r = 0; r < 4; ++r) acc[rti][nti][r] += bv;
  }
}
__device__ __forceinline__ void addB2(f32x4 acc[2][2], const float* bvec, int ntB, int lane16) {
#pragma unroll
  for (int nti = 0; nti < 2; ++nti) {
    float bv = bvec[(ntB + nti) * 16 + lane16];
#pragma unroll
    for (int rti = 0; rti < 2; ++rti)
#pragma unroll
      for (int r = 0; r < 4; ++r) acc[rti][nti][r] += bv;
  }
}
__device__ __forceinline__ void addE2(f32x4 acc[2][2], const float* __restrict__ E768,
                                      const int* __restrict__ tokS, int gateOff,
                                      int rtp, int ntB, int lane16, int lg) {
#pragma unroll
  for (int rti = 0; rti < 2; ++rti)
#pragma unroll
    for (int r = 0; r < 4; ++r) {
      int grow = (rtp * 2 + rti) * 16 + lg * 4 + r;
      const float* er = E768 + tokS[grow] * 768 + gateOff;
#pragma unroll
      for (int nti = 0; nti < 2; ++nti)
        acc[rti][nti][r] += er[(ntB + nti) * 16 + lane16];
    }
}

// LN over 256 cols/row in D-layout. red: [64 rows][4 cg][2].
__device__ __forceinline__ void lnD(f32x4 acc[2][4], int rtp, int cg, int lane16, int lg,
                                    float* red, const float* g, const float* b, bool relu) {
  float sv[2][4], qv[2][4];
#pragma unroll
  for (int rti = 0; rti < 2; ++rti)
#pragma unroll
    for (int r = 0; r < 4; ++r) {
      float s = 0.f, q = 0.f;
#pragma unroll
      for (int nti = 0; nti < 4; ++nti) { float v = acc[rti][nti][r]; s += v; q += v * v; }
#pragma unroll
      for (int m = 1; m < 16; m <<= 1) { s += __shfl_xor(s, m); q += __shfl_xor(q, m); }
      sv[rti][r] = s; qv[rti][r] = q;
    }
  __syncthreads();
  if (lane16 == 0) {
#pragma unroll
    for (int rti = 0; rti < 2; ++rti)
#pragma unroll
      for (int r = 0; r < 4; ++r) {
        int grow = (rtp * 2 + rti) * 16 + lg * 4 + r;
        red[grow * 8 + cg * 2] = sv[rti][r];
        red[grow * 8 + cg * 2 + 1] = qv[rti][r];
      }
  }
  __syncthreads();
  float gv[4], bv[4];
#pragma unroll
  for (int nti = 0; nti < 4; ++nti) {
    int gc = (cg * 4 + nti) * 16 + lane16;
    gv[nti] = g[gc]; bv[nti] = b[gc];
  }
#pragma unroll
  for (int rti = 0; rti < 2; ++rti)
#pragma unroll
    for (int r = 0; r < 4; ++r) {
      int grow = (rtp * 2 + rti) * 16 + lg * 4 + r;
      float s = red[grow * 8 + 0] + red[grow * 8 + 2] + red[grow * 8 + 4] + red[grow * 8 + 6];
      float q = red[grow * 8 + 1] + red[grow * 8 + 3] + red[grow * 8 + 5] + red[grow * 8 + 7];
      float mean = s * (1.f / 256.f);
      float var = q * (1.f / 256.f) - mean * mean;
      float rstd = rsqrtf(var + 1e-5f);
#pragma unroll
      for (int nti = 0; nti < 4; ++nti) {
        float v = (acc[rti][nti][r] - mean) * rstd * gv[nti] + bv[nti];
        acc[rti][nti][r] = relu ? fmaxf(v, 0.f) : v;
      }
    }
}

__device__ __forceinline__ void scatD(f16* X, const f32x4 acc[2][4], int rtp, int cg,
                                      int lane16, int lg) {
#pragma unroll
  for (int rti = 0; rti < 2; ++rti)
#pragma unroll
    for (int r = 0; r < 4; ++r) {
      int grow = (rtp * 2 + rti) * 16 + lg * 4 + r;
#pragma unroll
      for (int nti = 0; nti < 4; ++nti) {
        int gc = (cg * 4 + nti) * 16 + lane16;
        X[(size_t)grow * AST2 + gc] = (f16)acc[rti][nti][r];
      }
    }
}

__device__ __forceinline__ void stageH(f16* dst, const float* __restrict__ src,
                                       int nv, int t) {
#pragma unroll
  for (int ii = 0; ii < 4; ++ii) {
    int i = t + ii * TPM;
    int r = i >> 5, c8 = i & 31;
    f16x8 h = (f16x8)(_Float16)0;
    if (r < nv) {
      const float* p = src + (size_t)r * HD + c8 * 8;
      float4 v0 = *(const float4*)p, v1 = *(const float4*)(p + 4);
      h[0] = (f16)v0.x; h[1] = (f16)v0.y; h[2] = (f16)v0.z; h[3] = (f16)v0.w;
      h[4] = (f16)v1.x; h[5] = (f16)v1.y; h[6] = (f16)v1.z; h[7] = (f16)v1.w;
    }
    *(f16x8*)(dst + (size_t)r * AST2 + c8 * 8) = h;
  }
}

// ---------------- the f16-MFMA fused kernel (f32 world) ----------------
__global__ __launch_bounds__(TPM, 4) void k_mfma(
    const int* __restrict__ flag, int Brows,
    const float* __restrict__ node_i, const float* __restrict__ node_j,
    const float* __restrict__ latent, const float* __restrict__ hin,
    const int* __restrict__ tok,
    const float* __restrict__ be, const float* __restrict__ ge, const float* __restrict__ bee,
    const float* __restrict__ gn, const float* __restrict__ bn,
    const float* __restrict__ b_hh,
    const float* __restrict__ bfb, const float* __restrict__ gf, const float* __restrict__ bff,
    const float* __restrict__ b1, const float* __restrict__ W2, const float* __restrict__ b2,
    const f16* __restrict__ WeF, const f16* __restrict__ WihF,
    const f16* __restrict__ WhhF, const f16* __restrict__ WfF,
    const f16* __restrict__ W1F,
    const float* __restrict__ Wcvo, const float* __restrict__ bcvo,
    const float* __restrict__ E768,
    float* __restrict__ outL, float* __restrict__ outNH) {
  if (*flag != 0) return;
  extern __shared__ char smc[];
  f16* X1 = (f16*)smc;                         // [64][AST2]
  f16* X2 = (f16*)(smc + 33792);               // [64][AST2]
  float* red = (float*)(smc + 67584);          // 1024 f32
  float* sc  = (float*)(smc + 71680);          // 512 f32
  int* tokS  = (int*)(smc + 73728);            // 64 ints

  const int t = threadIdx.x;
  const int w = __builtin_amdgcn_readfirstlane(t >> 6);
  const int l = t & 63;
  const int lane16 = l & 15, lg = l >> 4;
  const int rtp = w & 1;
  const int cg = w >> 1;
  const int rowBase = rtp * 32;
  const int row0 = blockIdx.x * RPB;
  int nv = Brows - row0; if (nv > RPB) nv = RPB;

  if (t < 64) tokS[t] = (t < nv) ? tok[row0 + t] : 0;
  if (t < 512) sc[t] = ((t >> 3) < nv) ? latent[(size_t)row0 * 8 + t] : 0.f;
  stageH(X1, node_i + (size_t)row0 * HD, nv, t);
  __syncthreads();                                                  // B1

  // ---- EDGE = relu(LN([ni|nj]@We + be)) ----
  f32x4 acc[2][4];
  zero4(acc);
  mm4(acc, X1, rowBase, WeF, 16, 0, cg * 4, lane16, lg, l);
  __syncthreads();                                                  // B2
  stageH(X1, node_j + (size_t)row0 * HD, nv, t);
  __syncthreads();                                                  // B3
  mm4(acc, X1, rowBase, WeF, 16, 8, cg * 4, lane16, lg, l);
  addB4(acc, be, cg, lane16);
  lnD(acc, rtp, cg, lane16, lg, red, ge, bee, true);                // B4,B5
  scatD(X2, acc, rtp, cg, lane16, lg);                              // X2 = edge
  __syncthreads();                                                  // B6

  // ---- fusion acc: edge part ----
  f32x4 fac[2][4];
  zero4(fac);
  mm4(fac, X2, rowBase, WfF, 16, 0, cg * 4, lane16, lg, l);

  // ---- attended = LN(latent@Wcvo + bcvo) (VALU, K=8) -> X1 ----
  {
    float a32[32];
#pragma unroll
    for (int j4 = 0; j4 < 8; ++j4) {
      float4 v = *(const float4*)(bcvo + w * 32 + j4 * 4);
      a32[j4 * 4 + 0] = v.x; a32[j4 * 4 + 1] = v.y;
      a32[j4 * 4 + 2] = v.z; a32[j4 * 4 + 3] = v.w;
    }
#pragma unroll
    for (int k = 0; k < 8; ++k) {
      float xs = sc[l * 8 + k];
      const float* wr = Wcvo + k * 256 + w * 32;
#pragma unroll
      for (int j4 = 0; j4 < 8; ++j4) {
        float4 wv = *(const float4*)(wr + j4 * 4);
        a32[j4 * 4 + 0] = fmaf(xs, wv.x, a32[j4 * 4 + 0]);
        a32[j4 * 4 + 1] = fmaf(xs, wv.y, a32[j4 * 4 + 1]);
        a32[j4 * 4 + 2] = fmaf(xs, wv.z, a32[j4 * 4 + 2]);
        a32[j4 * 4 + 3] = fmaf(xs, wv.w, a32[j4 * 4 + 3]);
      }
    }
    float s = 0.f, q = 0.f;
#pragma unroll
    for (int j = 0; j < 32; ++j) { s += a32[j]; q += a32[j] * a32[j]; }
    __syncthreads();                                                // B7
    red[(w * 64 + l) * 2] = s; red[(w * 64 + l) * 2 + 1] = q;
    __syncthreads();                                                // B8
    s = 0.f; q = 0.f;
#pragma unroll
    for (int ww = 0; ww < 8; ++ww) {
      s += red[(ww * 64 + l) * 2]; q += red[(ww * 64 + l) * 2 + 1];
    }
    float mean = s * (1.f / 256.f);
    float var = q * (1.f / 256.f) - mean * mean;
    float rstd = rsqrtf(var + 1e-5f);
#pragma unroll
    for (int j = 0; j < 32; j += 2) {
      float v0 = (a32[j] - mean) * rstd * gn[w * 32 + j] + bn[w * 32 + j];
      float v1 = (a32[j + 1] - mean) * rstd * gn[w * 32 + j + 1] + bn[w * 32 + j + 1];
      union { f16 h[2]; unsigned u; } pu;
      pu.h[0] = (f16)v0; pu.h[1] = (f16)v1;
      *(unsigned*)(X1 + (size_t)l * AST2 + w * 32 + j) = pu.u;
    }
  }
  __syncthreads();                                                  // B9: X1 = attended

  // ---- fusion: att part; stage hin ----
  mm4(fac, X1, rowBase, WfF, 16, 8, cg * 4, lane16, lg, l);
  stageH(X2, hin + (size_t)row0 * HD, nv, t);
  __syncthreads();                                                  // B10: X2 = hin(f16)

  // ---- GRU: column-halved; newh straight to outNH (f32) ----
#pragma unroll
  for (int h = 0; h < 2; ++h) {
    const int ntB = cg * 4 + h * 2;   // 2 col-tiles = 32 cols
    f32x4 ghn[2][2];
    zero2(ghn);
    mmh(ghn, X2, rowBase, WhhF, 48, 32 + ntB, lane16, lg, l);
    addB2(ghn, b_hh + 512, ntB, lane16);

    f32x4 g2[2][2];
    zero2(g2);                         // acc_r
    mmh(g2, X1, rowBase, WihF, 48, ntB, lane16, lg, l);
    mmh(g2, X2, rowBase, WhhF, 48, ntB, lane16, lg, l);
    addE2(g2, E768, tokS, 0, rtp, ntB, lane16, lg);
    addB2(g2, b_hh, ntB, lane16);
#pragma unroll
    for (int a = 0; a < 2; ++a)
#pragma unroll
      for (int b = 0; b < 2; ++b)
#pragma unroll
        for (int r = 0; r < 4; ++r) {
          float rr = 1.f / (1.f + expf(-g2[a][b][r]));
          ghn[a][b][r] *= rr;          // ghn = r * ghn
        }

    zero2(g2);                         // gi_n
    mmh(g2, X1, rowBase, WihF, 48, 32 + ntB, lane16, lg, l);
    addE2(g2, E768, tokS, 512, rtp, ntB, lane16, lg);
#pragma unroll
    for (int a = 0; a < 2; ++a)
#pragma unroll
      for (int b = 0; b < 2; ++b)
#pragma unroll
        for (int r = 0; r < 4; ++r)
          ghn[a][b][r] = tanhf(g2[a][b][r] + ghn[a][b][r]);  // ghn = n

    zero2(g2);                         // acc_z
    mmh(g2, X1, rowBase, WihF, 48, 16 + ntB, lane16, lg, l);
    mmh(g2, X2, rowBase, WhhF, 48, 16 + ntB, lane16, lg, l);
    addE2(g2, E768, tokS, 256, rtp, ntB, lane16, lg);
    addB2(g2, b_hh + 256, ntB, lane16);
#pragma unroll
    for (int a = 0; a < 2; ++a)
#pragma unroll
      for (int r = 0; r < 4; ++r) {
        int grow = (rtp * 2 + a) * 16 + lg * 4 + r;
        bool live = grow < nv;
        float* orow = outNH + (size_t)(row0 + grow) * HD;
#pragma unroll
        for (int b = 0; b < 2; ++b) {
          int gc = (ntB + b) * 16 + lane16;
          float zz = 1.f / (1.f + expf(-g2[a][b][r]));
          float hv = (float)X2[(size_t)grow * AST2 + gc];
          float nh = (1.f - zz) * ghn[a][b][r] + zz * hv;
          if (live) orow[gc] = nh;
        }
      }
  }
  __syncthreads();                                                  // B11: outNH visible

  // ---- fusion: newh part (re-read outNH, L2-hot); fused = relu(LN(.)) ----
  mm4g(fac, outNH + (size_t)row0 * HD, rowBase, WfF, 16, 16, cg * 4, lane16, lg, l);
  addB4(fac, bfb, cg, lane16);
  lnD(fac, rtp, cg, lane16, lg, red, gf, bff, true);                // B12,B13
  scatD(X2, fac, rtp, cg, lane16, lg);                              // X2 = fused
  __syncthreads();                                                  // B14

  // ---- head: h1 = relu(fused@W1 + b1) ----
  f32x4 acc1[2][2];
  zero2(acc1);
  mmh(acc1, X2, rowBase, W1F, 8, cg * 2, lane16, lg, l);
  float* H = (float*)X1;               // [64][132] f32 (att dead)
#pragma unroll
  for (int a = 0; a < 2; ++a)
#pragma unroll
    for (int r = 0; r < 4; ++r) {
      int grow = (rtp * 2 + a) * 16 + lg * 4 + r;
#pragma unroll
      for (int b = 0; b < 2; ++b) {
        int gc1 = (cg * 2 + b) * 16 + lane16;
        H[grow * 132 + gc1] = fmaxf(acc1[a][b][r] + b1[gc1], 0.f);
      }
    }
  __syncthreads();                                                  // B15

  // ---- logits = h1@W2 + b2 (split-K over 8 waves) ----
  {
    int rr = t & 63, ks = w * 16;
    float p[8];
#pragma unroll
    for (int o = 0; o < 8; ++o) p[o] = 0.f;
    for (int k = 0; k < 16; ++k) {
      float hv = H[rr * 132 + ks + k];
      const float* w2r = W2 + (size_t)(ks + k) * 8;
#pragma unroll
      for (int o = 0; o < 8; ++o) p[o] = fmaf(hv, w2r[o], p[o]);
    }
    float* hp = (float*)X2;            // fused consumed by mmh pre-B15
#pragma unroll
    for (int o = 0; o < 8; ++o) hp[(w * 64 + rr) * 8 + o] = p[o];
  }
  __syncthreads();                                                  // B16
  if (t < 64 && t < nv) {
    const float* hp = (const float*)X2;
    float o8[8];
#pragma unroll
    for (int o = 0; o < 8; ++o) {
      float s = b2[o];
#pragma unroll
      for (int ww = 0; ww < 8; ++ww) s += hp[(ww * 64 + t) * 8 + o];
      o8[o] = s;
    }
    *(float4*)(outL + (size_t)(row0 + t) * 8) = make_float4(o8[0], o8[1], o8[2], o8[3]);
    *(float4*)(outL + (size_t)(row0 + t) * 8 + 4) = make_float4(o8[4], o8[5], o8[6], o8[7]);
  }
}

// ================= VALU fallback path (R5 structure, verified) =================
template <int K, int LDW, class XT, class WT>
__device__ __forceinline__ void gemm16(float* __restrict__ acc, const XT* __restrict__ x,
                                       const WT* __restrict__ wb) {
#pragma unroll 2
  for (int k = 0; k < K; k += 4) {
    float4 xv = ld4c(x + k);
#pragma unroll
    for (int kk = 0; kk < 4; ++kk) {
      float xs = (kk == 0) ? xv.x : (kk == 1) ? xv.y : (kk == 2) ? xv.z : xv.w;
      const WT* wr = wb + (size_t)(k + kk) * LDW;
#pragma unroll
      for (int j = 0; j < 4; ++j) {
        float4 wv = ld4c(wr + j * 4);
        acc[j*4+0] = fmaf(xs, wv.x, acc[j*4+0]);
        acc[j*4+1] = fmaf(xs, wv.y, acc[j*4+1]);
        acc[j*4+2] = fmaf(xs, wv.z, acc[j*4+2]);
        acc[j*4+3] = fmaf(xs, wv.w, acc[j*4+3]);
      }
    }
  }
}

template <int K, int LDW, class XT, class WT>
__device__ __forceinline__ void gemm8(float* __restrict__ acc, const XT* __restrict__ x,
                                      const WT* __restrict__ wb) {
#pragma unroll 2
  for (int k = 0; k < K; k += 4) {
    float4 xv = ld4c(x + k);
#pragma unroll
    for (int kk = 0; kk < 4; ++kk) {
      float xs = (kk == 0) ? xv.x : (kk == 1) ? xv.y : (kk == 2) ? xv.z : xv.w;
      const WT* wr = wb + (size_t)(k + kk) * LDW;
#pragma unroll
      for (int j = 0; j < 2; ++j) {
        float4 wv = ld4c(wr + j * 4);
        acc[j*4+0] = fmaf(xs, wv.x, acc[j*4+0]);
        acc[j*4+1] = fmaf(xs, wv.y, acc[j*4+1]);
        acc[j*4+2] = fmaf(xs, wv.z, acc[j*4+2]);
        acc[j*4+3] = fmaf(xs, wv.w, acc[j*4+3]);
      }
    }
  }
}

template <class WT>
__device__ __forceinline__ void ld16v(float* d, const WT* p) {
#pragma unroll
  for (int j = 0; j < 4; ++j) {
    float4 v = ld4c(p + j * 4);
    d[j*4+0] = v.x; d[j*4+1] = v.y; d[j*4+2] = v.z; d[j*4+3] = v.w;
  }
}
template <class WT>
__device__ __forceinline__ void add16v(float* d, const WT* p) {
#pragma unroll
  for (int j = 0; j < 4; ++j) {
    float4 v = ld4c(p + j * 4);
    d[j*4+0] += v.x; d[j*4+1] += v.y; d[j*4+2] += v.z; d[j*4+3] += v.w;
  }
}
__device__ __forceinline__ void st16v(float* p, const float* a) {
#pragma unroll
  for (int j = 0; j < 4; ++j)
    *(float4*)(p + j * 4) = make_float4(a[j*4+0], a[j*4+1], a[j*4+2], a[j*4+3]);
}

template <bool RELU, class WT>
__device__ __forceinline__ void ln_apply16(float* acc, float mean, float rstd,
                                           const WT* g, const WT* b) {
#pragma unroll
  for (int j = 0; j < 4; ++j) {
    float4 gv = ld4c(g + j * 4), bv = ld4c(b + j * 4);
    acc[j*4+0] = (acc[j*4+0] - mean) * rstd * gv.x + bv.x;
    acc[j*4+1] = (acc[j*4+1] - mean) * rstd * gv.y + bv.y;
    acc[j*4+2] = (acc[j*4+2] - mean) * rstd * gv.z + bv.z;
    acc[j*4+3] = (acc[j*4+3] - mean) * rstd * gv.w + bv.w;
    if (RELU) {
      acc[j*4+0] = fmaxf(acc[j*4+0], 0.f);
      acc[j*4+1] = fmaxf(acc[j*4+1], 0.f);
      acc[j*4+2] = fmaxf(acc[j*4+2], 0.f);
      acc[j*4+3] = fmaxf(acc[j*4+3], 0.f);
    }
  }
}

__device__ __forceinline__ void ln_stats16(const float* acc, int w, int l, float* red,
                                           float& mean, float& rstd) {
  float s = 0.f, q = 0.f;
#pragma unroll
  for (int j = 0; j < 16; ++j) { s += acc[j]; q += acc[j] * acc[j]; }
  __syncthreads();
  *(float2*)(red + (w * 64 + l) * 2) = make_float2(s, q);
  __syncthreads();
  s = 0.f; q = 0.f;
#pragma unroll
  for (int ww = 0; ww < 16; ++ww) {
    float2 v = *(const float2*)(red + (ww * 64 + l) * 2);
    s += v.x; q += v.y;
  }
  mean = s * (1.f / 256.f);
  float var = q * (1.f / 256.f) - mean * mean;
  rstd = rsqrtf(var + 1e-5f);
}

template <class T>
__device__ __forceinline__ void stage256(float* dst, const T* __restrict__ src, int nv, int t) {
#pragma unroll
  for (int ii = 0; ii < 4; ++ii) {
    int i = t + ii * TPB;
    int r = i >> 6, c4 = i & 63;
    float4 v = make_float4(0.f, 0.f, 0.f, 0.f);
    if (r < nv) v = ld4c(src + (size_t)r * HD + c4 * 4);
    *(float4*)(dst + r * AST + c4 * 4) = v;
  }
}

template <class T, class WT, int WANT>
__global__ __launch_bounds__(TPB, 4) void k_row(
    const int* __restrict__ flag, int Brows,
    const T* __restrict__ node_i, const T* __restrict__ node_j,
    const T* __restrict__ latent, const T* __restrict__ hin,
    const int* __restrict__ tok,
    const WT* __restrict__ We, const WT* __restrict__ be,
    const WT* __restrict__ ge, const WT* __restrict__ bee,
    const WT* __restrict__ gn, const WT* __restrict__ bn,
    const WT* __restrict__ emb,
    const WT* __restrict__ W_ih, const WT* __restrict__ b_ih,
    const WT* __restrict__ W_hh, const WT* __restrict__ b_hh,
    const WT* __restrict__ Wf, const WT* __restrict__ bfb,
    const WT* __restrict__ gf, const WT* __restrict__ bff,
    const WT* __restrict__ W1, const WT* __restrict__ b1,
    const WT* __restrict__ W2, const WT* __restrict__ b2,
    const float* __restrict__ Wcvo, const float* __restrict__ bcvo,
    T* __restrict__ outL, T* __restrict__ outNH) {
  if (*flag != WANT) return;
  extern __shared__ float sm[];
  float* A   = sm;
  float* Bb  = sm + 64 * AST;
  float* red = sm + 2 * 64 * AST;
  float* sc  = red + 2048;
  int* tokS  = (int*)(sc + 512);

  const int t = threadIdx.x;
  const int w = __builtin_amdgcn_readfirstlane(t >> 6);
  const int l = t & 63;
  const int row0 = blockIdx.x * RPB;
  int nv = Brows - row0; if (nv > RPB) nv = RPB;
  const int cb = w * 16;

  if (t < 64) tokS[t] = (t < nv) ? tok[row0 + t] : 0;
  stage256(A, node_i + (size_t)row0 * HD, nv, t);
  __syncthreads();

  float acc[16];
  ld16v(acc, be + cb);
  gemm16<256, 256>(acc, A + l * AST, We + cb);
  __syncthreads();
  stage256(A, node_j + (size_t)row0 * HD, nv, t);
  __syncthreads();
  gemm16<256, 256>(acc, A + l * AST, We + (size_t)256 * 256 + cb);
  float mean, rstd;
  ln_stats16(acc, w, l, red, mean, rstd);
  ln_apply16<true>(acc, mean, rstd, ge + cb, bee + cb);
  st16v(Bb + l * AST + cb, acc);
  __syncthreads();

  float fac[16];
  ld16v(fac, bfb + cb);
  gemm16<256, 256>(fac, Bb + l * AST, Wf + cb);

  if (t < 512) {
    int r = t >> 3;
    sc[t] = (r < nv) ? ld(latent + (size_t)row0 * 8 + t) : 0.f;
  }
  __syncthreads();
  ld16v(acc, bcvo + cb);
  gemm16<8, 256>(acc, sc + l * 8, Wcvo + cb);
  ln_stats16(acc, w, l, red, mean, rstd);
  ln_apply16<false>(acc, mean, rstd, gn + cb, bn + cb);
  st16v(A + l * AST + cb, acc);
  __syncthreads();

  gemm16<256, 256>(fac, A + l * AST, Wf + (size_t)256 * 256 + cb);
  stage256(Bb, hin + (size_t)row0 * HD, nv, t);
  __syncthreads();

  const int tk = tokS[l];
  const WT* embr = emb + (size_t)tk * HD;

  ld16v(acc, b_ih + cb); add16v(acc, b_hh + cb);
  gemm16<256, 768>(acc, A + l * AST, W_ih + cb);
  gemm16<256, 768>(acc, embr, W_ih + (size_t)256 * 768 + cb);
  gemm16<256, 768>(acc, Bb + l * AST, W_hh + cb);
  float rg[16];
#pragma unroll
  for (int j = 0; j < 16; ++j) rg[j] = 1.f / (1.f + expf(-acc[j]));

  ld16v(acc, b_hh + 512 + cb);
  gemm16<256, 768>(acc, Bb + l * AST, W_hh + 512 + cb);
#pragma unroll
  for (int j = 0; j < 16; ++j) rg[j] *= acc[j];

  ld16v(acc, b_ih + 512 + cb);
  gemm16<256, 768>(acc, A + l * AST, W_ih + 512 + cb);
  gemm16<256, 768>(acc, embr, W_ih + (size_t)256 * 768 + 512 + cb);
#pragma unroll
  for (int j = 0; j < 16; ++j) rg[j] = tanhf(acc[j] + rg[j]);

  ld16v(acc, b_ih + 256 + cb); add16v(acc, b_hh + 256 + cb);
  gemm16<256, 768>(acc, A + l * AST, W_ih + 256 + cb);
  gemm16<256, 768>(acc, embr, W_ih + (size_t)256 * 768 + 256 + cb);
  gemm16<256, 768>(acc, Bb + l * AST, W_hh + 256 + cb);
  __syncthreads();
#pragma unroll
  for (int j4 = 0; j4 < 4; ++j4) {
    float4 hv = ld4c(Bb + l * AST + cb + j4 * 4);
    float z0 = 1.f / (1.f + expf(-acc[j4*4+0]));
    float z1 = 1.f / (1.f + expf(-acc[j4*4+1]));
    float z2 = 1.f / (1.f + expf(-acc[j4*4+2]));
    float z3 = 1.f / (1.f + expf(-acc[j4*4+3]));
    acc[j4*4+0] = (1.f - z0) * rg[j4*4+0] + z0 * hv.x;
    acc[j4*4+1] = (1.f - z1) * rg[j4*4+1] + z1 * hv.y;
    acc[j4*4+2] = (1.f - z2) * rg[j4*4+2] + z2 * hv.z;
    acc[j4*4+3] = (1.f - z3) * rg[j4*4+3] + z3 * hv.w;
  }
  st16v(Bb + l * AST + cb, acc);
  __syncthreads();

  for (int i = t; i < nv * HD; i += TPB) {
    int r = i >> 8, c = i & 255;
    outNH[(size_t)(row0 + r) * HD + c] = (T)Bb[r * AST + c];
  }

  gemm16<256, 256>(fac, Bb + l * AST, Wf + (size_t)512 * 256 + cb);
  ln_stats16(fac, w, l, red, mean, rstd);
  ln_apply16<true>(fac, mean, rstd, gf + cb, bff + cb);
  st16v(A + l * AST + cb, fac);
  __syncthreads();

  float h1[8];
  {
    float4 v0 = ld4c(b1 + w * 8), v1 = ld4c(b1 + w * 8 + 4);
    h1[0]=v0.x; h1[1]=v0.y; h1[2]=v0.z; h1[3]=v0.w;
    h1[4]=v1.x; h1[5]=v1.y; h1[6]=v1.z; h1[7]=v1.w;
  }
  gemm8<256, 128>(h1, A + l * AST, W1 + w * 8);
  float part[8];
#pragma unroll
  for (int o = 0; o < 8; ++o) part[o] = 0.f;
#pragma unroll
  for (int kk = 0; kk < 8; ++kk) {
    float hval = fmaxf(h1[kk], 0.f);
    const WT* w2r = W2 + (size_t)(w * 8 + kk) * 8;
    float4 a0 = ld4c(w2r), a1 = ld4c(w2r + 4);
    part[0] = fmaf(hval, a0.x, part[0]);
    part[1] = fmaf(hval, a0.y, part[1]);
    part[2] = fmaf(hval, a0.z, part[2]);
    part[3] = fmaf(hval, a0.w, part[3]);
    part[4] = fmaf(hval, a1.x, part[4]);
    part[5] = fmaf(hval, a1.y, part[5]);
    part[6] = fmaf(hval, a1.z, part[6]);
    part[7] = fmaf(hval, a1.w, part[7]);
  }
  float* hp = Bb;
  *(float4*)(hp + (w * 64 + l) * 8)     = make_float4(part[0], part[1], part[2], part[3]);
  *(float4*)(hp + (w * 64 + l) * 8 + 4) = make_float4(part[4], part[5], part[6], part[7]);
  __syncthreads();
  if (w == 0 && l < nv) {
#pragma unroll
    for (int o = 0; o < 8; ++o) {
      float lg = ld(b2 + o);
#pragma unroll
      for (int ww = 0; ww < 16; ++ww) lg += hp[(ww * 64 + l) * 8 + o];
      outL[(size_t)(row0 + l) * 8 + o] = (T)lg;
    }
  }
}

// ---------------- launch ----------------
extern "C" void kernel_launch(void* const* d_in, const int* in_sizes, int n_in,
                              void* d_out, int out_size, void* d_ws, size_t ws_size,
                              hipStream_t stream) {
  char* ws = (char*)d_ws;
  const int B = in_sizes[0] / HD;
  const int nblk = (B + RPB - 1) / RPB;
  int* flag = (int*)ws;
  float* tmpcv = (float*)(ws + 1024);
  float* Wcvo  = (float*)(ws + 16384);
  float* bcvo  = (float*)(ws + 24576);
  float* E768  = (float*)(ws + 28672);
  f16*   fragW = (f16*)(ws + FB_OFF);
  const int doPrep = (ws_size >= (size_t)WS_NEED) ? 1 : 0;

  int nw = B * 128; if (nw > 16384) nw = 16384;
  k_detect<<<1, 256, 0, stream>>>((const unsigned int*)d_in[0], flag, nw);

  k_pre1<<<529, 256, 0, stream>>>(flag, doPrep,
      d_in[5], d_in[22], d_in[24], d_in[26], d_in[30],   // We,Wih,Whh,Wf,W1
      d_in[21], d_in[23],                                // emb, b_ih
      d_in[9], d_in[15], d_in[10], d_in[16],             // Wc,Wv,bc,bv
      fragW, E768, tmpcv);
  k_pre2<<<9, 256, 0, stream>>>(flag, tmpcv, d_in[17], d_in[18], Wcvo, bcvo);

  const size_t SMEM_F = (size_t)(2 * 64 * AST + 2048 + 512) * 4 + 64 * 4;
  const size_t SMEM_M = 73984;

  // ---- f32 world: f16 MFMA (fallback: VALU k_row) ----
  {
    auto P = [&](int i) { return (const float*)d_in[i]; };
    if (doPrep) {
      (void)hipFuncSetAttribute(reinterpret_cast<const void*>(&k_mfma),
                                hipFuncAttributeMaxDynamicSharedMemorySize, (int)SMEM_M);
      k_mfma<<<nblk, TPM, SMEM_M, stream>>>(
          flag, B, P(0), P(1), P(2), P(3), (const int*)d_in[4],
          P(6), P(7), P(8),                 // be, ge, bee
          P(19), P(20),                     // gn, bn
          P(25),                            // b_hh
          P(27), P(28), P(29),              // bfb, gf, bff
          P(31), P(32), P(33),              // b1, W2, b2
          fragW + WE_E, fragW + WIH_E, fragW + WHH_E, fragW + WF_E, fragW + W1_E,
          Wcvo, bcvo, E768,
          (float*)d_out, (float*)d_out + (size_t)B * 8);
    } else {
      (void)hipFuncSetAttribute(reinterpret_cast<const void*>(&k_row<float, float, 0>),
                                hipFuncAttributeMaxDynamicSharedMemorySize, (int)SMEM_F);
      k_row<float, float, 0><<<nblk, TPB, SMEM_F, stream>>>(
          flag, B, P(0), P(1), P(2), P(3), (const int*)d_in[4],
          P(5), P(6), P(7), P(8), P(19), P(20), P(21),
          P(22), P(23), P(24), P(25), P(26), P(27), P(28), P(29),
          P(30), P(31), P(32), P(33), Wcvo, bcvo,
          (float*)d_out, (float*)d_out + (size_t)B * 8);
    }
  }
  // ---- bf16 world (never observed live; safe fallback) ----
  {
    auto P = [&](int i) { return (const bf16*)d_in[i]; };
    bf16* oL = (bf16*)d_out;
    (void)hipFuncSetAttribute(reinterpret_cast<const void*>(&k_row<bf16, bf16, 1>),
                              hipFuncAttributeMaxDynamicSharedMemorySize, (int)SMEM_F);
    k_row<bf16, bf16, 1><<<nblk, TPB, SMEM_F, stream>>>(
        flag, B, P(0), P(1), P(2), P(3), (const int*)d_in[4],
        P(5), P(6), P(7), P(8), P(19), P(20), P(21),
        P(22), P(23), P(24), P(25), P(26), P(27), P(28), P(29),
        P(30), P(31), P(32), P(33), Wcvo, bcvo, oL, oL + (size_t)B * 8);
  }
}